// Round 8
// baseline (382.651 us; speedup 1.0000x reference)
//
#include <hip/hip_runtime.h>
#include <stdint.h>

#define NROWS 1024
#define CDIM  4096
#define KDIM  16384
#define SIDE  128

typedef __attribute__((ext_vector_type(8))) short short8;
typedef __attribute__((ext_vector_type(4))) float f32x4;
typedef __attribute__((ext_vector_type(16))) float f32x16;

static __device__ __forceinline__ unsigned short f2bf(float f) {
  unsigned u = __float_as_uint(f);
  u += 0x7fffu + ((u >> 16) & 1u);   // round-to-nearest-even
  return (unsigned short)(u >> 16);
}
static __device__ __forceinline__ float bf2f(unsigned short h) {
  return __uint_as_float(((unsigned)h) << 16);
}

#define GLOAD_LDS16(g, l)                                                     \
  __builtin_amdgcn_global_load_lds(                                           \
      (const __attribute__((address_space(1))) void*)(g),                     \
      (__attribute__((address_space(3))) void*)(l), 16, 0, 0)

// 128B-row XOR-swizzle (PROVEN 0 conflicts in R3/R4/R5 counters): 16B-chunk
// bits [6:4] ^= row bits [9:7]. Involution; 16B-aligned; row-preserving.
#define SWZ(o) ((o) ^ (((o) >> 3) & 0x70))

// ---------- init: w2 = 0, rowmin = +inf ----------
__global__ void k_zero(float* __restrict__ w2, unsigned* __restrict__ rowmin) {
  int i = blockIdx.x * 256 + threadIdx.x;
  w2[i] = 0.f;
  if (i < NROWS) rowmin[i] = 0x7f7fffffu;  // FLT_MAX bits
}

// ---------- weights: f32 [c][k] -> bf16 hi/lo transposed [k][c]; fused w2 ----
__global__ __launch_bounds__(256) void k_wconv(const float* __restrict__ w,
                                               unsigned short* __restrict__ whT,
                                               unsigned short* __restrict__ wlT,
                                               float* __restrict__ w2) {
  __shared__ float T[64][65];
  const int k0 = blockIdx.x * 64, c0 = blockIdx.y * 64;
  const int t = threadIdx.x;
#pragma unroll
  for (int i = 0; i < 4; i++) {
    int e = i * 1024 + t * 4;
    int cr = e >> 6, kc = e & 63;
    float4 v = *(const float4*)(w + (size_t)(c0 + cr) * KDIM + k0 + kc);
    T[cr][kc] = v.x; T[cr][kc + 1] = v.y; T[cr][kc + 2] = v.z; T[cr][kc + 3] = v.w;
  }
  __syncthreads();
#pragma unroll
  for (int i = 0; i < 4; i++) {
    int e = i * 1024 + t * 4;
    int kr = e >> 6, cc = e & 63;
    ushort4 hv, lv;
    float f0 = T[cc + 0][kr], f1 = T[cc + 1][kr];
    float f2 = T[cc + 2][kr], f3 = T[cc + 3][kr];
    hv.x = f2bf(f0); lv.x = f2bf(f0 - bf2f(hv.x));
    hv.y = f2bf(f1); lv.y = f2bf(f1 - bf2f(hv.y));
    hv.z = f2bf(f2); lv.z = f2bf(f2 - bf2f(hv.z));
    hv.w = f2bf(f3); lv.w = f2bf(f3 - bf2f(hv.w));
    size_t off = (size_t)(k0 + kr) * CDIM + c0 + cc;
    *(ushort4*)(whT + off) = hv;
    *(ushort4*)(wlT + off) = lv;
    float s = f0 * f0 + f1 * f1 + f2 * f2 + f3 * f3;
#pragma unroll
    for (int off2 = 8; off2 > 0; off2 >>= 1) s += __shfl_down(s, off2);
    if ((t & 15) == 0) atomicAdd(&w2[k0 + kr], s);
  }
}

// ---------- x: f32 [n][c] -> bf16 ----------
__global__ __launch_bounds__(256) void k_xconv(const float* __restrict__ x,
                                               unsigned short* __restrict__ xh) {
  size_t i = ((size_t)blockIdx.x * 256 + threadIdx.x) * 4;
  float4 v = *(const float4*)(x + i);
  ushort4 hv;
  hv.x = f2bf(v.x); hv.y = f2bf(v.y); hv.z = f2bf(v.z); hv.w = f2bf(v.w);
  *(ushort4*)(xh + i) = hv;
}

// ---------- x2[n] = sum_c x^2 ----------
__global__ void k_x2(const float* __restrict__ x, float* __restrict__ x2) {
  const int n = blockIdx.x, l = threadIdx.x;  // 64 threads
  const float* row = x + (size_t)n * CDIM;
  float s = 0.f;
#pragma unroll 4
  for (int i = 0; i < 16; i++) {
    float4 v = *(const float4*)(row + (i * 64 + l) * 4);
    s += v.x * v.x + v.y * v.y + v.z * v.z + v.w * v.w;
  }
#pragma unroll
  for (int off = 32; off > 0; off >>= 1) s += __shfl_down(s, off);
  if (l == 0) x2[n] = s;
}

// ---------- main MFMA GEMM: BM=BN=256, BK=64, 8 waves (2M x 4N) ----------
// R5-proven structure: whole-tile stage (8 gload_lds), counted vmcnt(8),
// 2 barriers/tile, 128KB dbuf LDS, SWZ layout (0-conflict proven).
// NEW: 32x32x16 MFMA (half the instruction count, ~15% better rate) and
// fused per-row min (uint atomicMin on clamped norms2) for k_row.
__global__ __launch_bounds__(512, 2) void k_gemm(
    const unsigned short* __restrict__ xh,
    const unsigned short* __restrict__ whT,
    const float* __restrict__ x2, const float* __restrict__ w2,
    float* __restrict__ out, unsigned* __restrict__ rowmin) {
  extern __shared__ char smem[];  // 131072 B: dbuf d at d*65536; A +0, B +32768
  const int t = threadIdx.x;
  const int b = blockIdx.x;
  const int L = (b & 7) * 32 + (b >> 3);   // XCD-bijective (256 wgs)
  const int m0 = (L & 3) * 256, n0 = (L >> 2) * 256;
  const int lane = t & 63, wid = t >> 6;
  const int wrow = (wid >> 2) * 128;   // wave M-half: 0 or 128
  const int wcol = (wid & 3) * 64;     // wave N-quarter
  const int r31 = lane & 31;
  const int hk = lane >> 5;            // k-half within a K=16 step
  const int hk16 = hk * 16;            // ...as byte offset (8 bf16)

  // staging geometry (rule #21, R5-proven): linear LDS chunk o_lin holds
  // logical chunk SWZ(o_lin) of the operand tile.
  int rowS[4], cbS[4];
  uint32_t loffS[4];
#pragma unroll
  for (int i = 0; i < 4; i++) {
    int o_lin = (i * 512 + t) * 16;
    int o_log = SWZ(o_lin);
    rowS[i] = o_log >> 7;          // 0..255
    cbS[i] = (o_log & 127) >> 1;   // element col 0..63
    loffS[i] = i * 8192 + wid * 1024;  // wave-uniform linear LDS base
  }

  f32x16 acc[4][2];
#pragma unroll
  for (int m = 0; m < 4; m++)
#pragma unroll
    for (int n = 0; n < 2; n++)
#pragma unroll
      for (int q = 0; q < 16; q++) acc[m][n][q] = 0.f;

#define STAGE_TILE(tt, d)                                                     \
  {                                                                           \
    const int c0s = (tt) * 64;                                                \
    char* const dst = smem + (d) * 65536;                                     \
    _Pragma("unroll")                                                         \
    for (int i = 0; i < 4; i++) {                                             \
      size_t ga = (size_t)(m0 + rowS[i]) * CDIM + c0s + cbS[i];               \
      GLOAD_LDS16(xh + ga, dst + loffS[i]);                                   \
    }                                                                         \
    _Pragma("unroll")                                                         \
    for (int i = 0; i < 4; i++) {                                             \
      size_t gb = (size_t)(n0 + rowS[i]) * CDIM + c0s + cbS[i];               \
      GLOAD_LDS16(whT + gb, dst + 32768 + loffS[i]);                          \
    }                                                                         \
  }

  STAGE_TILE(0, 0);  // prologue: 8 loads in flight

  for (int tl = 0; tl < 64; ++tl) {
    const int cur = tl & 1;
    if (tl < 63) {
      STAGE_TILE(tl + 1, cur ^ 1);  // 8 more loads; never drain to 0 (T4)
      asm volatile("s_waitcnt vmcnt(8)" ::: "memory");  // tile tl landed
    } else {
      asm volatile("s_waitcnt vmcnt(0)" ::: "memory");
    }
    asm volatile("s_barrier" ::: "memory");  // all waves' loads landed

    const char* const Ab = smem + cur * 65536;
    const char* const Bb = Ab + 32768;
    __builtin_amdgcn_s_setprio(1);
#pragma unroll
    for (int ks = 0; ks < 4; ks++) {
      const int kb = ks * 32 + hk16;
      short8 b0 = *(const short8*)(Bb + SWZ((wcol + r31) * 128 + kb));
      short8 b1 = *(const short8*)(Bb + SWZ((wcol + 32 + r31) * 128 + kb));
#pragma unroll
      for (int m = 0; m < 4; m++) {
        short8 am = *(const short8*)(Ab + SWZ((wrow + m * 32 + r31) * 128 + kb));
        acc[m][0] = __builtin_amdgcn_mfma_f32_32x32x16_bf16(am, b0, acc[m][0], 0, 0, 0);
        acc[m][1] = __builtin_amdgcn_mfma_f32_32x32x16_bf16(am, b1, acc[m][1], 0, 0, 0);
      }
    }
    __builtin_amdgcn_s_setprio(0);
    asm volatile("s_barrier" ::: "memory");  // reads done; buf reusable
  }
#undef STAGE_TILE

  // epilogue: norms2 = max(x2 + w2 - 2*xw, 0); fused per-row min -> atomicMin
  const float w2v0 = w2[n0 + wcol + r31];
  const float w2v1 = w2[n0 + wcol + 32 + r31];
#pragma unroll
  for (int m = 0; m < 4; m++) {
#pragma unroll
    for (int reg = 0; reg < 16; reg++) {
      int row = m0 + wrow + m * 32 + (reg & 3) + 8 * (reg >> 2) + 4 * hk;
      float xr = x2[row];
      float* orow = out + (size_t)row * KDIM;
      float v0 = xr + w2v0 - 2.0f * acc[m][0][reg];
      float v1 = xr + w2v1 - 2.0f * acc[m][1][reg];
      v0 = v0 < 0.f ? 0.f : v0;
      v1 = v1 < 0.f ? 0.f : v1;
      orow[n0 + wcol + r31] = v0;
      orow[n0 + wcol + 32 + r31] = v1;
      float vm = fminf(v0, v1);
#pragma unroll
      for (int msk = 1; msk <= 16; msk <<= 1) vm = fminf(vm, __shfl_xor(vm, msk));
      if (r31 == 0) atomicMin(&rowmin[row], __float_as_uint(vm));
    }
  }
}

// ---------- fallback fp32 GEMM (exact), used only if ws too small ----------
__global__ __launch_bounds__(256) void k_fb(const float* __restrict__ x,
                                            const float* __restrict__ w,
                                            float* __restrict__ out) {
  __shared__ float xs[16][65];
  __shared__ float wsm[16][65];
  const int t = threadIdx.x;
  const int n0 = blockIdx.x * 64, k0 = blockIdx.y * 64;
  const int tx = t & 15, ty = t >> 4;
  float acc[4][4];
#pragma unroll
  for (int a = 0; a < 4; a++)
#pragma unroll
    for (int b = 0; b < 4; b++) acc[a][b] = 0.f;
  for (int c0 = 0; c0 < CDIM; c0 += 16) {
#pragma unroll
    for (int i = 0; i < 4; i++) {
      int e = i * 256 + t;
      int nl = e >> 4, cl = e & 15;
      xs[cl][nl] = x[(size_t)(n0 + nl) * CDIM + c0 + cl];
    }
#pragma unroll
    for (int i = 0; i < 4; i++) {
      int e = i * 256 + t;
      int cl = e >> 6, kl = e & 63;
      wsm[cl][kl] = w[(size_t)(c0 + cl) * KDIM + k0 + kl];
    }
    __syncthreads();
#pragma unroll
    for (int c = 0; c < 16; c++)
#pragma unroll
      for (int a = 0; a < 4; a++) {
        float xa = xs[c][ty * 4 + a];
#pragma unroll
        for (int b = 0; b < 4; b++) {
          float d = wsm[c][tx * 4 + b] - xa;
          acc[a][b] += d * d;
        }
      }
    __syncthreads();
  }
#pragma unroll
  for (int a = 0; a < 4; a++)
#pragma unroll
    for (int b = 0; b < 4; b++)
      out[(size_t)(n0 + ty * 4 + a) * KDIM + k0 + tx * 4 + b] = acc[a][b];
}

// ---------- per-row: candidates (thr from GEMM rowmin) -> refine -> RBF ----
__global__ __launch_bounds__(256) void k_row(
    float* __restrict__ out, const float* __restrict__ stdp,
    const float* __restrict__ x, const unsigned short* __restrict__ whT,
    const unsigned short* __restrict__ wlT, const float* __restrict__ w2,
    const unsigned* __restrict__ rowmin) {
  const int n = blockIdx.x, t = threadIdx.x;
  __shared__ alignas(16) float er[SIDE];
  __shared__ alignas(16) float ec[SIDE];
  __shared__ float s_red[4];
  __shared__ int cand[128];
  __shared__ int s_ncand;
  __shared__ int s_bmu;
  __shared__ float s_inv;
  float* row = out + (size_t)n * KDIM;

  if (t == 0) s_ncand = 0;
  __syncthreads();
  const float thr = __uint_as_float(rowmin[n]) + 0.05f;

  // collect candidate indices within the safety window (single pass)
#pragma unroll 4
  for (int i = 0; i < 16; i++) {
    int k = (t + i * 256) * 4;
    float4 v = *(const float4*)(row + k);
    if (v.x <= thr) { int j = atomicAdd(&s_ncand, 1); if (j < 128) cand[j] = k; }
    if (v.y <= thr) { int j = atomicAdd(&s_ncand, 1); if (j < 128) cand[j] = k + 1; }
    if (v.z <= thr) { int j = atomicAdd(&s_ncand, 1); if (j < 128) cand[j] = k + 2; }
    if (v.w <= thr) { int j = atomicAdd(&s_ncand, 1); if (j < 128) cand[j] = k + 3; }
  }
  __syncthreads();
  int nc = s_ncand < 128 ? s_ncand : 128;

  // refine: exact score = w2[k] - 2 * dot(x_f32, wh+wl) per candidate
  float best = 3.4e38f;
  int bestk = 0x7fffffff;
  const float* xr = x + (size_t)n * CDIM;
  for (int j = 0; j < nc; j++) {
    const int k = cand[j];
    const unsigned short* wh = whT + (size_t)k * CDIM;
    const unsigned short* wl = wlT + (size_t)k * CDIM;
    float s = 0.f;
#pragma unroll
    for (int ii = 0; ii < 2; ii++) {
      int c = (ii * 256 + t) * 8;
      short8 h8 = *(const short8*)(wh + c);
      short8 l8 = *(const short8*)(wl + c);
      float4 xa = *(const float4*)(xr + c);
      float4 xb = *(const float4*)(xr + c + 4);
      s += xa.x * (bf2f((unsigned short)h8[0]) + bf2f((unsigned short)l8[0]));
      s += xa.y * (bf2f((unsigned short)h8[1]) + bf2f((unsigned short)l8[1]));
      s += xa.z * (bf2f((unsigned short)h8[2]) + bf2f((unsigned short)l8[2]));
      s += xa.w * (bf2f((unsigned short)h8[3]) + bf2f((unsigned short)l8[3]));
      s += xb.x * (bf2f((unsigned short)h8[4]) + bf2f((unsigned short)l8[4]));
      s += xb.y * (bf2f((unsigned short)h8[5]) + bf2f((unsigned short)l8[5]));
      s += xb.z * (bf2f((unsigned short)h8[6]) + bf2f((unsigned short)l8[6]));
      s += xb.w * (bf2f((unsigned short)h8[7]) + bf2f((unsigned short)l8[7]));
    }
#pragma unroll
    for (int off = 32; off > 0; off >>= 1) s += __shfl_down(s, off);
    if ((t & 63) == 0) s_red[t >> 6] = s;
    __syncthreads();
    if (t == 0) {
      float dot = s_red[0] + s_red[1] + s_red[2] + s_red[3];
      float sc = w2[k] - 2.0f * dot;
      if (sc < best || (sc == best && k < bestk)) { best = sc; bestk = k; }
    }
    __syncthreads();
  }
  if (t == 0) s_bmu = bestk;
  __syncthreads();

  const int bmu = s_bmu;
  const float sd = stdp[0];
  const float inv2s2 = -0.5f / (sd * sd);
  const float rr = (float)(bmu >> 7), ccol = (float)(bmu & 127);
  if (t < 128) {
    float d = (float)t - rr;
    er[t] = expf(d * d * inv2s2);
  } else {
    int j = t - 128;
    float d = (float)j - ccol;
    ec[j] = expf(d * d * inv2s2);
  }
  __syncthreads();
  if (t == 0) {
    float Sr = 0.f, Sc = 0.f;
    for (int i = 0; i < SIDE; i++) { Sr += er[i]; Sc += ec[i]; }
    s_inv = 1.0f / (Sr * Sc);
  }
  __syncthreads();
  const float inv = s_inv;
#pragma unroll 4
  for (int i = 0; i < 16; i++) {
    int k = (t + i * 256) * 4;
    float4 v = *(const float4*)(row + k);
    float e_r = er[k >> 7] * inv;
    const float4 e4 = *(const float4*)(&ec[k & 127]);
    v.x *= e_r * e4.x;
    v.y *= e_r * e4.y;
    v.z *= e_r * e4.z;
    v.w *= e_r * e4.w;
    *(float4*)(row + k) = v;
  }
}

// ---------- fallback per-row (exact norms2 from k_fb) ----------
__global__ __launch_bounds__(256) void k_row_fb(float* __restrict__ out,
                                                const float* __restrict__ stdp) {
  const int n = blockIdx.x, t = threadIdx.x;
  __shared__ alignas(16) float er[SIDE];
  __shared__ alignas(16) float ec[SIDE];
  __shared__ float rv[4];
  __shared__ int ri[4];
  __shared__ float s_inv;
  __shared__ int s_bmu;
  float* row = out + (size_t)n * KDIM;

  float bv = 3.4e38f;
  int bi = 0;
#pragma unroll 4
  for (int i = 0; i < 16; i++) {
    int k = (t + i * 256) * 4;
    float4 v = *(const float4*)(row + k);
    if (v.x < bv) { bv = v.x; bi = k; }
    if (v.y < bv) { bv = v.y; bi = k + 1; }
    if (v.z < bv) { bv = v.z; bi = k + 2; }
    if (v.w < bv) { bv = v.w; bi = k + 3; }
  }
#pragma unroll
  for (int off = 32; off > 0; off >>= 1) {
    float ov = __shfl_down(bv, off);
    int oi = __shfl_down(bi, off);
    if (ov < bv || (ov == bv && oi < bi)) { bv = ov; bi = oi; }
  }
  if ((t & 63) == 0) { rv[t >> 6] = bv; ri[t >> 6] = bi; }
  __syncthreads();
  if (t == 0) {
    for (int i = 1; i < 4; i++)
      if (rv[i] < bv || (rv[i] == bv && ri[i] < bi)) { bv = rv[i]; bi = ri[i]; }
    s_bmu = bi;
  }
  __syncthreads();
  const int bmu = s_bmu;
  const float sd = stdp[0];
  const float inv2s2 = -0.5f / (sd * sd);
  const float rr = (float)(bmu >> 7), ccol = (float)(bmu & 127);
  if (t < 128) {
    float d = (float)t - rr;
    er[t] = expf(d * d * inv2s2);
  } else {
    int j = t - 128;
    float d = (float)j - ccol;
    ec[j] = expf(d * d * inv2s2);
  }
  __syncthreads();
  if (t == 0) {
    float Sr = 0.f, Sc = 0.f;
    for (int i = 0; i < SIDE; i++) { Sr += er[i]; Sc += ec[i]; }
    s_inv = 1.0f / (Sr * Sc);
  }
  __syncthreads();
  const float inv = s_inv;
#pragma unroll 4
  for (int i = 0; i < 16; i++) {
    int k = (t + i * 256) * 4;
    float4 v = *(const float4*)(row + k);
    float e_r = er[k >> 7] * inv;
    const float4 e4 = *(const float4*)(&ec[k & 127]);
    v.x *= e_r * e4.x;
    v.y *= e_r * e4.y;
    v.z *= e_r * e4.z;
    v.w *= e_r * e4.w;
    *(float4*)(row + k) = v;
  }
}

extern "C" void kernel_launch(void* const* d_in, const int* in_sizes, int n_in,
                              void* d_out, int out_size, void* d_ws, size_t ws_size,
                              hipStream_t stream) {
  (void)in_sizes; (void)n_in; (void)out_size;
  const float* x = (const float*)d_in[0];
  const float* w = (const float*)d_in[1];
  const float* stdp = (const float*)d_in[2];
  float* out = (float*)d_out;

  const size_t sz_wT = (size_t)KDIM * CDIM * sizeof(unsigned short);  // 128 MiB each
  const size_t sz_x  = (size_t)NROWS * CDIM * sizeof(unsigned short); // 8 MiB
  const size_t need = 2 * sz_wT + sz_x + (size_t)NROWS * 4 + (size_t)KDIM * 4 +
                      (size_t)NROWS * 4;

  if (ws_size >= need) {
    char* p = (char*)d_ws;
    unsigned short* whT = (unsigned short*)p; p += sz_wT;
    unsigned short* wlT = (unsigned short*)p; p += sz_wT;
    unsigned short* xh  = (unsigned short*)p; p += sz_x;
    float* x2 = (float*)p; p += (size_t)NROWS * 4;
    float* w2 = (float*)p; p += (size_t)KDIM * 4;
    unsigned* rowmin = (unsigned*)p;

    // allow 128 KB dynamic LDS for k_gemm (host-side, idempotent, capture-safe)
    static int lds_ok = -1;
    if (lds_ok < 0)
      lds_ok = (int)hipFuncSetAttribute((const void*)k_gemm,
                                        hipFuncAttributeMaxDynamicSharedMemorySize,
                                        131072);

    k_zero<<<KDIM / 256, 256, 0, stream>>>(w2, rowmin);
    k_wconv<<<dim3(KDIM / 64, CDIM / 64), 256, 0, stream>>>(w, whT, wlT, w2);
    k_xconv<<<(NROWS * CDIM) / 1024, 256, 0, stream>>>(x, xh);
    k_x2<<<NROWS, 64, 0, stream>>>(x, x2);
    k_gemm<<<256, 512, 131072, stream>>>(xh, whT, x2, w2, out, rowmin);
    k_row<<<NROWS, 256, 0, stream>>>(out, stdp, x, whT, wlT, w2, rowmin);
  } else {
    k_fb<<<dim3(NROWS / 64, KDIM / 64), 256, 0, stream>>>(x, w, out);
    k_row_fb<<<NROWS, 256, 0, stream>>>(out, stdp);
  }
}

// Round 9
// 320.980 us; speedup vs baseline: 1.1921x; 1.1921x over previous
//
#include <hip/hip_runtime.h>
#include <stdint.h>

#define NROWS 1024
#define CDIM  4096
#define KDIM  16384
#define SIDE  128

typedef __attribute__((ext_vector_type(8))) short short8;
typedef __attribute__((ext_vector_type(4))) float f32x4;

static __device__ __forceinline__ unsigned short f2bf(float f) {
  unsigned u = __float_as_uint(f);
  u += 0x7fffu + ((u >> 16) & 1u);   // round-to-nearest-even
  return (unsigned short)(u >> 16);
}
static __device__ __forceinline__ float bf2f(unsigned short h) {
  return __uint_as_float(((unsigned)h) << 16);
}

#define GLOAD_LDS16(g, l)                                                     \
  __builtin_amdgcn_global_load_lds(                                           \
      (const __attribute__((address_space(1))) void*)(g),                     \
      (__attribute__((address_space(3))) void*)(l), 16, 0, 0)

// 128B-row XOR-swizzle (PROVEN 0 conflicts in R3/R4/R5 counters with the
// 16-row x 4-kgroup fragment pattern): 16B-chunk bits [6:4] ^= row bits
// [9:7]. Involution; 16B-aligned; row-preserving.
#define SWZ(o) ((o) ^ (((o) >> 3) & 0x70))

// ---------- init: w2 = 0, rowmin = +inf ----------
__global__ void k_zero(float* __restrict__ w2, unsigned* __restrict__ rowmin) {
  int i = blockIdx.x * 256 + threadIdx.x;
  w2[i] = 0.f;
  if (i < NROWS) rowmin[i] = 0x7f7fffffu;  // FLT_MAX bits
}

// ---------- weights: f32 [c][k] -> bf16 hi/lo transposed [k][c]; fused w2 ----
__global__ __launch_bounds__(256) void k_wconv(const float* __restrict__ w,
                                               unsigned short* __restrict__ whT,
                                               unsigned short* __restrict__ wlT,
                                               float* __restrict__ w2) {
  __shared__ float T[64][65];
  const int k0 = blockIdx.x * 64, c0 = blockIdx.y * 64;
  const int t = threadIdx.x;
#pragma unroll
  for (int i = 0; i < 4; i++) {
    int e = i * 1024 + t * 4;
    int cr = e >> 6, kc = e & 63;
    float4 v = *(const float4*)(w + (size_t)(c0 + cr) * KDIM + k0 + kc);
    T[cr][kc] = v.x; T[cr][kc + 1] = v.y; T[cr][kc + 2] = v.z; T[cr][kc + 3] = v.w;
  }
  __syncthreads();
#pragma unroll
  for (int i = 0; i < 4; i++) {
    int e = i * 1024 + t * 4;
    int kr = e >> 6, cc = e & 63;
    ushort4 hv, lv;
    float f0 = T[cc + 0][kr], f1 = T[cc + 1][kr];
    float f2 = T[cc + 2][kr], f3 = T[cc + 3][kr];
    hv.x = f2bf(f0); lv.x = f2bf(f0 - bf2f(hv.x));
    hv.y = f2bf(f1); lv.y = f2bf(f1 - bf2f(hv.y));
    hv.z = f2bf(f2); lv.z = f2bf(f2 - bf2f(hv.z));
    hv.w = f2bf(f3); lv.w = f2bf(f3 - bf2f(hv.w));
    size_t off = (size_t)(k0 + kr) * CDIM + c0 + cc;
    *(ushort4*)(whT + off) = hv;
    *(ushort4*)(wlT + off) = lv;
    float s = f0 * f0 + f1 * f1 + f2 * f2 + f3 * f3;
#pragma unroll
    for (int off2 = 8; off2 > 0; off2 >>= 1) s += __shfl_down(s, off2);
    if ((t & 15) == 0) atomicAdd(&w2[k0 + kr], s);
  }
}

// ---------- x: f32 [n][c] -> bf16 ----------
__global__ __launch_bounds__(256) void k_xconv(const float* __restrict__ x,
                                               unsigned short* __restrict__ xh) {
  size_t i = ((size_t)blockIdx.x * 256 + threadIdx.x) * 4;
  float4 v = *(const float4*)(x + i);
  ushort4 hv;
  hv.x = f2bf(v.x); hv.y = f2bf(v.y); hv.z = f2bf(v.z); hv.w = f2bf(v.w);
  *(ushort4*)(xh + i) = hv;
}

// ---------- x2[n] = sum_c x^2 ----------
__global__ void k_x2(const float* __restrict__ x, float* __restrict__ x2) {
  const int n = blockIdx.x, l = threadIdx.x;  // 64 threads
  const float* row = x + (size_t)n * CDIM;
  float s = 0.f;
#pragma unroll 4
  for (int i = 0; i < 16; i++) {
    float4 v = *(const float4*)(row + (i * 64 + l) * 4);
    s += v.x * v.x + v.y * v.y + v.z * v.z + v.w * v.w;
  }
#pragma unroll
  for (int off = 32; off > 0; off >>= 1) s += __shfl_down(s, off);
  if (l == 0) x2[n] = s;
}

// ---------- main MFMA GEMM: BM=BN=256, BK=64, 8 waves (2M x 4N) ----------
// R5-PROVEN structure (143 us, 0 conflicts): 16x16x32 MFMA, whole-tile stage
// (8 gload_lds), counted vmcnt(8), 2 barriers/tile, 128KB dbuf LDS, SWZ.
// Added: fused per-row min (shfl_xor over rlo + atomicMin) for k_row.
__global__ __launch_bounds__(512, 2) void k_gemm(
    const unsigned short* __restrict__ xh,
    const unsigned short* __restrict__ whT,
    const float* __restrict__ x2, const float* __restrict__ w2,
    float* __restrict__ out, unsigned* __restrict__ rowmin) {
  extern __shared__ char smem[];  // 131072 B: dbuf d at d*65536; A +0, B +32768
  const int t = threadIdx.x;
  const int b = blockIdx.x;
  const int L = (b & 7) * 32 + (b >> 3);   // XCD-bijective (256 wgs)
  const int m0 = (L & 3) * 256, n0 = (L >> 2) * 256;
  const int lane = t & 63, wid = t >> 6;
  const int wrow = (wid >> 2) * 128;   // wave M-half: 0 or 128
  const int wcol = (wid & 3) * 64;     // wave N-quarter
  const int rlo = lane & 15;
  const int kgb = (lane >> 4) * 16;    // k-group byte offset in a K=32 slice

  // staging geometry (rule #21): linear LDS chunk o_lin holds logical chunk
  // SWZ(o_lin) of the operand tile.
  int rowS[4], cbS[4];
  uint32_t loffS[4];
#pragma unroll
  for (int i = 0; i < 4; i++) {
    int o_lin = (i * 512 + t) * 16;
    int o_log = SWZ(o_lin);
    rowS[i] = o_log >> 7;          // 0..255
    cbS[i] = (o_log & 127) >> 1;   // element col 0..63
    loffS[i] = i * 8192 + wid * 1024;  // wave-uniform linear LDS base
  }

  f32x4 acc[8][4];
#pragma unroll
  for (int m = 0; m < 8; m++)
#pragma unroll
    for (int n = 0; n < 4; n++) acc[m][n] = (f32x4){0.f, 0.f, 0.f, 0.f};

#define STAGE_TILE(tt, d)                                                     \
  {                                                                           \
    const int c0s = (tt) * 64;                                                \
    char* const dst = smem + (d) * 65536;                                     \
    _Pragma("unroll")                                                         \
    for (int i = 0; i < 4; i++) {                                             \
      size_t ga = (size_t)(m0 + rowS[i]) * CDIM + c0s + cbS[i];               \
      GLOAD_LDS16(xh + ga, dst + loffS[i]);                                   \
    }                                                                         \
    _Pragma("unroll")                                                         \
    for (int i = 0; i < 4; i++) {                                             \
      size_t gb = (size_t)(n0 + rowS[i]) * CDIM + c0s + cbS[i];               \
      GLOAD_LDS16(whT + gb, dst + 32768 + loffS[i]);                          \
    }                                                                         \
  }

  STAGE_TILE(0, 0);  // prologue: 8 loads in flight

  for (int tl = 0; tl < 64; ++tl) {
    const int cur = tl & 1;
    if (tl < 63) {
      STAGE_TILE(tl + 1, cur ^ 1);  // 8 more loads; never drain to 0 (T4)
      asm volatile("s_waitcnt vmcnt(8)" ::: "memory");  // tile tl landed
    } else {
      asm volatile("s_waitcnt vmcnt(0)" ::: "memory");
    }
    asm volatile("s_barrier" ::: "memory");  // all waves' loads landed

    const char* const Ab = smem + cur * 65536;
    const char* const Bb = Ab + 32768;
    short8 b_f[4][2];
#pragma unroll
    for (int n = 0; n < 4; n++)
#pragma unroll
      for (int ks = 0; ks < 2; ks++)
        b_f[n][ks] = *(const short8*)(Bb + SWZ((wcol + n * 16 + rlo) * 128 + ks * 64 + kgb));
    __builtin_amdgcn_s_setprio(1);
#pragma unroll
    for (int m = 0; m < 8; m++) {
      short8 a0 = *(const short8*)(Ab + SWZ((wrow + m * 16 + rlo) * 128 + kgb));
      short8 a1 = *(const short8*)(Ab + SWZ((wrow + m * 16 + rlo) * 128 + 64 + kgb));
#pragma unroll
      for (int n = 0; n < 4; n++) {
        acc[m][n] = __builtin_amdgcn_mfma_f32_16x16x32_bf16(a0, b_f[n][0], acc[m][n], 0, 0, 0);
        acc[m][n] = __builtin_amdgcn_mfma_f32_16x16x32_bf16(a1, b_f[n][1], acc[m][n], 0, 0, 0);
      }
    }
    __builtin_amdgcn_s_setprio(0);
    asm volatile("s_barrier" ::: "memory");  // reads done; buf reusable
  }
#undef STAGE_TILE

  // epilogue: norms2 = max(x2 + w2 - 2*xw, 0); fused per-row min
  float w2v[4];
#pragma unroll
  for (int n = 0; n < 4; n++) w2v[n] = w2[n0 + wcol + n * 16 + rlo];
#pragma unroll
  for (int m = 0; m < 8; m++) {
#pragma unroll
    for (int j = 0; j < 4; j++) {
      int row = m0 + wrow + m * 16 + (lane >> 4) * 4 + j;
      float xr = x2[row];
      float* orow = out + (size_t)row * KDIM;
      float vm = 3.4e38f;
#pragma unroll
      for (int n = 0; n < 4; n++) {
        int col = n0 + wcol + n * 16 + rlo;
        float v = xr + w2v[n] - 2.0f * acc[m][n][j];
        v = v < 0.f ? 0.f : v;
        orow[col] = v;
        vm = fminf(vm, v);
      }
      // reduce over the 16 rlo lanes of this row-quadrant (masks flip rlo)
#pragma unroll
      for (int msk = 1; msk <= 8; msk <<= 1) vm = fminf(vm, __shfl_xor(vm, msk));
      if (rlo == 0) atomicMin(&rowmin[row], __float_as_uint(vm));
    }
  }
}

// ---------- fallback fp32 GEMM (exact), used only if ws too small ----------
__global__ __launch_bounds__(256) void k_fb(const float* __restrict__ x,
                                            const float* __restrict__ w,
                                            float* __restrict__ out) {
  __shared__ float xs[16][65];
  __shared__ float wsm[16][65];
  const int t = threadIdx.x;
  const int n0 = blockIdx.x * 64, k0 = blockIdx.y * 64;
  const int tx = t & 15, ty = t >> 4;
  float acc[4][4];
#pragma unroll
  for (int a = 0; a < 4; a++)
#pragma unroll
    for (int b = 0; b < 4; b++) acc[a][b] = 0.f;
  for (int c0 = 0; c0 < CDIM; c0 += 16) {
#pragma unroll
    for (int i = 0; i < 4; i++) {
      int e = i * 256 + t;
      int nl = e >> 4, cl = e & 15;
      xs[cl][nl] = x[(size_t)(n0 + nl) * CDIM + c0 + cl];
    }
#pragma unroll
    for (int i = 0; i < 4; i++) {
      int e = i * 256 + t;
      int cl = e >> 6, kl = e & 63;
      wsm[cl][kl] = w[(size_t)(c0 + cl) * KDIM + k0 + kl];
    }
    __syncthreads();
#pragma unroll
    for (int c = 0; c < 16; c++)
#pragma unroll
      for (int a = 0; a < 4; a++) {
        float xa = xs[c][ty * 4 + a];
#pragma unroll
        for (int b = 0; b < 4; b++) {
          float d = wsm[c][tx * 4 + b] - xa;
          acc[a][b] += d * d;
        }
      }
    __syncthreads();
  }
#pragma unroll
  for (int a = 0; a < 4; a++)
#pragma unroll
    for (int b = 0; b < 4; b++)
      out[(size_t)(n0 + ty * 4 + a) * KDIM + k0 + tx * 4 + b] = acc[a][b];
}

// ---------- per-row: candidates (thr from GEMM rowmin) -> refine -> RBF ----
__global__ __launch_bounds__(256) void k_row(
    float* __restrict__ out, const float* __restrict__ stdp,
    const float* __restrict__ x, const unsigned short* __restrict__ whT,
    const unsigned short* __restrict__ wlT, const float* __restrict__ w2,
    const unsigned* __restrict__ rowmin) {
  const int n = blockIdx.x, t = threadIdx.x;
  __shared__ alignas(16) float er[SIDE];
  __shared__ alignas(16) float ec[SIDE];
  __shared__ float s_red[4];
  __shared__ int cand[128];
  __shared__ int s_ncand;
  __shared__ int s_bmu;
  __shared__ float s_inv;
  float* row = out + (size_t)n * KDIM;

  if (t == 0) s_ncand = 0;
  __syncthreads();
  const float thr = __uint_as_float(rowmin[n]) + 0.05f;

  // collect candidate indices within the safety window (single pass)
#pragma unroll 4
  for (int i = 0; i < 16; i++) {
    int k = (t + i * 256) * 4;
    float4 v = *(const float4*)(row + k);
    if (v.x <= thr) { int j = atomicAdd(&s_ncand, 1); if (j < 128) cand[j] = k; }
    if (v.y <= thr) { int j = atomicAdd(&s_ncand, 1); if (j < 128) cand[j] = k + 1; }
    if (v.z <= thr) { int j = atomicAdd(&s_ncand, 1); if (j < 128) cand[j] = k + 2; }
    if (v.w <= thr) { int j = atomicAdd(&s_ncand, 1); if (j < 128) cand[j] = k + 3; }
  }
  __syncthreads();
  int nc = s_ncand < 128 ? s_ncand : 128;

  // refine: exact score = w2[k] - 2 * dot(x_f32, wh+wl) per candidate
  float best = 3.4e38f;
  int bestk = 0x7fffffff;
  const float* xr = x + (size_t)n * CDIM;
  for (int j = 0; j < nc; j++) {
    const int k = cand[j];
    const unsigned short* wh = whT + (size_t)k * CDIM;
    const unsigned short* wl = wlT + (size_t)k * CDIM;
    float s = 0.f;
#pragma unroll
    for (int ii = 0; ii < 2; ii++) {
      int c = (ii * 256 + t) * 8;
      short8 h8 = *(const short8*)(wh + c);
      short8 l8 = *(const short8*)(wl + c);
      float4 xa = *(const float4*)(xr + c);
      float4 xb = *(const float4*)(xr + c + 4);
      s += xa.x * (bf2f((unsigned short)h8[0]) + bf2f((unsigned short)l8[0]));
      s += xa.y * (bf2f((unsigned short)h8[1]) + bf2f((unsigned short)l8[1]));
      s += xa.z * (bf2f((unsigned short)h8[2]) + bf2f((unsigned short)l8[2]));
      s += xa.w * (bf2f((unsigned short)h8[3]) + bf2f((unsigned short)l8[3]));
      s += xb.x * (bf2f((unsigned short)h8[4]) + bf2f((unsigned short)l8[4]));
      s += xb.y * (bf2f((unsigned short)h8[5]) + bf2f((unsigned short)l8[5]));
      s += xb.z * (bf2f((unsigned short)h8[6]) + bf2f((unsigned short)l8[6]));
      s += xb.w * (bf2f((unsigned short)h8[7]) + bf2f((unsigned short)l8[7]));
    }
#pragma unroll
    for (int off = 32; off > 0; off >>= 1) s += __shfl_down(s, off);
    if ((t & 63) == 0) s_red[t >> 6] = s;
    __syncthreads();
    if (t == 0) {
      float dot = s_red[0] + s_red[1] + s_red[2] + s_red[3];
      float sc = w2[k] - 2.0f * dot;
      if (sc < best || (sc == best && k < bestk)) { best = sc; bestk = k; }
    }
    __syncthreads();
  }
  if (t == 0) s_bmu = bestk;
  __syncthreads();

  const int bmu = s_bmu;
  const float sd = stdp[0];
  const float inv2s2 = -0.5f / (sd * sd);
  const float rr = (float)(bmu >> 7), ccol = (float)(bmu & 127);
  if (t < 128) {
    float d = (float)t - rr;
    er[t] = expf(d * d * inv2s2);
  } else {
    int j = t - 128;
    float d = (float)j - ccol;
    ec[j] = expf(d * d * inv2s2);
  }
  __syncthreads();
  if (t == 0) {
    float Sr = 0.f, Sc = 0.f;
    for (int i = 0; i < SIDE; i++) { Sr += er[i]; Sc += ec[i]; }
    s_inv = 1.0f / (Sr * Sc);
  }
  __syncthreads();
  const float inv = s_inv;
#pragma unroll 4
  for (int i = 0; i < 16; i++) {
    int k = (t + i * 256) * 4;
    float4 v = *(const float4*)(row + k);
    float e_r = er[k >> 7] * inv;
    const float4 e4 = *(const float4*)(&ec[k & 127]);
    v.x *= e_r * e4.x;
    v.y *= e_r * e4.y;
    v.z *= e_r * e4.z;
    v.w *= e_r * e4.w;
    *(float4*)(row + k) = v;
  }
}

// ---------- fallback per-row (exact norms2 from k_fb) ----------
__global__ __launch_bounds__(256) void k_row_fb(float* __restrict__ out,
                                                const float* __restrict__ stdp) {
  const int n = blockIdx.x, t = threadIdx.x;
  __shared__ alignas(16) float er[SIDE];
  __shared__ alignas(16) float ec[SIDE];
  __shared__ float rv[4];
  __shared__ int ri[4];
  __shared__ float s_inv;
  __shared__ int s_bmu;
  float* row = out + (size_t)n * KDIM;

  float bv = 3.4e38f;
  int bi = 0;
#pragma unroll 4
  for (int i = 0; i < 16; i++) {
    int k = (t + i * 256) * 4;
    float4 v = *(const float4*)(row + k);
    if (v.x < bv) { bv = v.x; bi = k; }
    if (v.y < bv) { bv = v.y; bi = k + 1; }
    if (v.z < bv) { bv = v.z; bi = k + 2; }
    if (v.w < bv) { bv = v.w; bi = k + 3; }
  }
#pragma unroll
  for (int off = 32; off > 0; off >>= 1) {
    float ov = __shfl_down(bv, off);
    int oi = __shfl_down(bi, off);
    if (ov < bv || (ov == bv && oi < bi)) { bv = ov; bi = oi; }
  }
  if ((t & 63) == 0) { rv[t >> 6] = bv; ri[t >> 6] = bi; }
  __syncthreads();
  if (t == 0) {
    for (int i = 1; i < 4; i++)
      if (rv[i] < bv || (rv[i] == bv && ri[i] < bi)) { bv = rv[i]; bi = ri[i]; }
    s_bmu = bi;
  }
  __syncthreads();
  const int bmu = s_bmu;
  const float sd = stdp[0];
  const float inv2s2 = -0.5f / (sd * sd);
  const float rr = (float)(bmu >> 7), ccol = (float)(bmu & 127);
  if (t < 128) {
    float d = (float)t - rr;
    er[t] = expf(d * d * inv2s2);
  } else {
    int j = t - 128;
    float d = (float)j - ccol;
    ec[j] = expf(d * d * inv2s2);
  }
  __syncthreads();
  if (t == 0) {
    float Sr = 0.f, Sc = 0.f;
    for (int i = 0; i < SIDE; i++) { Sr += er[i]; Sc += ec[i]; }
    s_inv = 1.0f / (Sr * Sc);
  }
  __syncthreads();
  const float inv = s_inv;
#pragma unroll 4
  for (int i = 0; i < 16; i++) {
    int k = (t + i * 256) * 4;
    float4 v = *(const float4*)(row + k);
    float e_r = er[k >> 7] * inv;
    const float4 e4 = *(const float4*)(&ec[k & 127]);
    v.x *= e_r * e4.x;
    v.y *= e_r * e4.y;
    v.z *= e_r * e4.z;
    v.w *= e_r * e4.w;
    *(float4*)(row + k) = v;
  }
}

extern "C" void kernel_launch(void* const* d_in, const int* in_sizes, int n_in,
                              void* d_out, int out_size, void* d_ws, size_t ws_size,
                              hipStream_t stream) {
  (void)in_sizes; (void)n_in; (void)out_size;
  const float* x = (const float*)d_in[0];
  const float* w = (const float*)d_in[1];
  const float* stdp = (const float*)d_in[2];
  float* out = (float*)d_out;

  const size_t sz_wT = (size_t)KDIM * CDIM * sizeof(unsigned short);  // 128 MiB each
  const size_t sz_x  = (size_t)NROWS * CDIM * sizeof(unsigned short); // 8 MiB
  const size_t need = 2 * sz_wT + sz_x + (size_t)NROWS * 4 + (size_t)KDIM * 4 +
                      (size_t)NROWS * 4;

  if (ws_size >= need) {
    char* p = (char*)d_ws;
    unsigned short* whT = (unsigned short*)p; p += sz_wT;
    unsigned short* wlT = (unsigned short*)p; p += sz_wT;
    unsigned short* xh  = (unsigned short*)p; p += sz_x;
    float* x2 = (float*)p; p += (size_t)NROWS * 4;
    float* w2 = (float*)p; p += (size_t)KDIM * 4;
    unsigned* rowmin = (unsigned*)p;

    // allow 128 KB dynamic LDS for k_gemm (host-side, idempotent, capture-safe)
    static int lds_ok = -1;
    if (lds_ok < 0)
      lds_ok = (int)hipFuncSetAttribute((const void*)k_gemm,
                                        hipFuncAttributeMaxDynamicSharedMemorySize,
                                        131072);

    k_zero<<<KDIM / 256, 256, 0, stream>>>(w2, rowmin);
    k_wconv<<<dim3(KDIM / 64, CDIM / 64), 256, 0, stream>>>(w, whT, wlT, w2);
    k_xconv<<<(NROWS * CDIM) / 1024, 256, 0, stream>>>(x, xh);
    k_x2<<<NROWS, 64, 0, stream>>>(x, x2);
    k_gemm<<<256, 512, 131072, stream>>>(xh, whT, x2, w2, out, rowmin);
    k_row<<<NROWS, 256, 0, stream>>>(out, stdp, x, whT, wlT, w2, rowmin);
  } else {
    k_fb<<<dim3(NROWS / 64, KDIM / 64), 256, 0, stream>>>(x, w, out);
    k_row_fb<<<NROWS, 256, 0, stream>>>(out, stdp);
  }
}

// Round 10
// 302.975 us; speedup vs baseline: 1.2630x; 1.0594x over previous
//
#include <hip/hip_runtime.h>
#include <stdint.h>

#define NROWS 1024
#define CDIM  4096
#define KDIM  16384
#define SIDE  128

typedef __attribute__((ext_vector_type(8))) short short8;
typedef __attribute__((ext_vector_type(4))) float f32x4;

static __device__ __forceinline__ unsigned short f2bf(float f) {
  unsigned u = __float_as_uint(f);
  u += 0x7fffu + ((u >> 16) & 1u);   // round-to-nearest-even
  return (unsigned short)(u >> 16);
}
static __device__ __forceinline__ float bf2f(unsigned short h) {
  return __uint_as_float(((unsigned)h) << 16);
}

#define GLOAD_LDS16(g, l)                                                     \
  __builtin_amdgcn_global_load_lds(                                           \
      (const __attribute__((address_space(1))) void*)(g),                     \
      (__attribute__((address_space(3))) void*)(l), 16, 0, 0)

// 128B-row XOR-swizzle (PROVEN 0 conflicts R3/R4/R9 with the 16-row x
// 4-kgroup fragment pattern): 16B-chunk bits [6:4] ^= row bits [9:7].
// Involution; 16B-aligned; row-preserving.
#define SWZ(o) ((o) ^ (((o) >> 3) & 0x70))

// ---------- prep: xh = bf16(x), x2[n] = sum x^2, w2 = 0 (merged) ----------
__global__ __launch_bounds__(256) void k_prep(const float* __restrict__ x,
                                              unsigned short* __restrict__ xh,
                                              float* __restrict__ x2,
                                              float* __restrict__ w2) {
  const int n = blockIdx.x, t = threadIdx.x;
  __shared__ float rv[4];
  if (n < 64) w2[n * 256 + t] = 0.f;  // zero w2 (16384 floats over 64 blocks)
  const float* row = x + (size_t)n * CDIM;
  unsigned short* xrow = xh + (size_t)n * CDIM;
  float s = 0.f;
#pragma unroll
  for (int i = 0; i < 4; i++) {
    int e = (t + i * 256) * 4;
    float4 v = *(const float4*)(row + e);
    ushort4 hv;
    hv.x = f2bf(v.x); hv.y = f2bf(v.y); hv.z = f2bf(v.z); hv.w = f2bf(v.w);
    *(ushort4*)(xrow + e) = hv;
    s += v.x * v.x + v.y * v.y + v.z * v.z + v.w * v.w;
  }
#pragma unroll
  for (int off = 32; off > 0; off >>= 1) s += __shfl_down(s, off);
  if ((t & 63) == 0) rv[t >> 6] = s;
  __syncthreads();
  if (t == 0) x2[n] = rv[0] + rv[1] + rv[2] + rv[3];
}

// ---------- weights: f32 [c][k] -> bf16 hi/lo transposed [k][c]; fused w2 ----
__global__ __launch_bounds__(256) void k_wconv(const float* __restrict__ w,
                                               unsigned short* __restrict__ whT,
                                               unsigned short* __restrict__ wlT,
                                               float* __restrict__ w2) {
  __shared__ float T[64][65];
  const int k0 = blockIdx.x * 64, c0 = blockIdx.y * 64;
  const int t = threadIdx.x;
#pragma unroll
  for (int i = 0; i < 4; i++) {
    int e = i * 1024 + t * 4;
    int cr = e >> 6, kc = e & 63;
    float4 v = *(const float4*)(w + (size_t)(c0 + cr) * KDIM + k0 + kc);
    T[cr][kc] = v.x; T[cr][kc + 1] = v.y; T[cr][kc + 2] = v.z; T[cr][kc + 3] = v.w;
  }
  __syncthreads();
#pragma unroll
  for (int i = 0; i < 4; i++) {
    int e = i * 1024 + t * 4;
    int kr = e >> 6, cc = e & 63;
    ushort4 hv, lv;
    float f0 = T[cc + 0][kr], f1 = T[cc + 1][kr];
    float f2 = T[cc + 2][kr], f3 = T[cc + 3][kr];
    hv.x = f2bf(f0); lv.x = f2bf(f0 - bf2f(hv.x));
    hv.y = f2bf(f1); lv.y = f2bf(f1 - bf2f(hv.y));
    hv.z = f2bf(f2); lv.z = f2bf(f2 - bf2f(hv.z));
    hv.w = f2bf(f3); lv.w = f2bf(f3 - bf2f(hv.w));
    size_t off = (size_t)(k0 + kr) * CDIM + c0 + cc;
    *(ushort4*)(whT + off) = hv;
    *(ushort4*)(wlT + off) = lv;
    float s = f0 * f0 + f1 * f1 + f2 * f2 + f3 * f3;
#pragma unroll
    for (int off2 = 8; off2 > 0; off2 >>= 1) s += __shfl_down(s, off2);
    if ((t & 15) == 0) atomicAdd(&w2[k0 + kr], s);
  }
}

// ---------- main MFMA GEMM: BM=BN=256, BK=64, 8 waves (2M x 4N) ----------
// R4-PROVEN body (293-total config): 16x16x32 MFMA, whole-tile stage
// (8 gload_lds), counted vmcnt(8), 2 barriers/tile, 128KB dbuf LDS, SWZ,
// setprio around MFMA cluster, XCD-bijective block mapping. NO epilogue
// extras (fused rowmin cost +25-35us in R9 -> removed).
__global__ __launch_bounds__(512, 2) void k_gemm(
    const unsigned short* __restrict__ xh,
    const unsigned short* __restrict__ whT,
    const float* __restrict__ x2, const float* __restrict__ w2,
    float* __restrict__ out) {
  extern __shared__ char smem[];  // 131072 B: dbuf d at d*65536; A +0, B +32768
  const int t = threadIdx.x;
  const int b = blockIdx.x;
  const int L = (b & 7) * 32 + (b >> 3);   // XCD-bijective (256 wgs)
  const int m0 = (L & 3) * 256, n0 = (L >> 2) * 256;
  const int lane = t & 63, wid = t >> 6;
  const int wrow = (wid >> 2) * 128;   // wave M-half: 0 or 128
  const int wcol = (wid & 3) * 64;     // wave N-quarter
  const int rlo = lane & 15;
  const int kgb = (lane >> 4) * 16;    // k-group byte offset in a K=32 slice

  // staging geometry (rule #21): linear LDS chunk o_lin holds logical chunk
  // SWZ(o_lin) of the operand tile.
  int rowS[4], cbS[4];
  uint32_t loffS[4];
#pragma unroll
  for (int i = 0; i < 4; i++) {
    int o_lin = (i * 512 + t) * 16;
    int o_log = SWZ(o_lin);
    rowS[i] = o_log >> 7;          // 0..255
    cbS[i] = (o_log & 127) >> 1;   // element col 0..63
    loffS[i] = i * 8192 + wid * 1024;  // wave-uniform linear LDS base
  }

  f32x4 acc[8][4];
#pragma unroll
  for (int m = 0; m < 8; m++)
#pragma unroll
    for (int n = 0; n < 4; n++) acc[m][n] = (f32x4){0.f, 0.f, 0.f, 0.f};

#define STAGE_TILE(tt, d)                                                     \
  {                                                                           \
    const int c0s = (tt) * 64;                                                \
    char* const dst = smem + (d) * 65536;                                     \
    _Pragma("unroll")                                                         \
    for (int i = 0; i < 4; i++) {                                             \
      size_t ga = (size_t)(m0 + rowS[i]) * CDIM + c0s + cbS[i];               \
      GLOAD_LDS16(xh + ga, dst + loffS[i]);                                   \
    }                                                                         \
    _Pragma("unroll")                                                         \
    for (int i = 0; i < 4; i++) {                                             \
      size_t gb = (size_t)(n0 + rowS[i]) * CDIM + c0s + cbS[i];               \
      GLOAD_LDS16(whT + gb, dst + 32768 + loffS[i]);                          \
    }                                                                         \
  }

  STAGE_TILE(0, 0);  // prologue: 8 loads in flight

  for (int tl = 0; tl < 64; ++tl) {
    const int cur = tl & 1;
    if (tl < 63) {
      STAGE_TILE(tl + 1, cur ^ 1);  // 8 more loads; never drain to 0 (T4)
      asm volatile("s_waitcnt vmcnt(8)" ::: "memory");  // tile tl landed
    } else {
      asm volatile("s_waitcnt vmcnt(0)" ::: "memory");
    }
    asm volatile("s_barrier" ::: "memory");  // all waves' loads landed

    const char* const Ab = smem + cur * 65536;
    const char* const Bb = Ab + 32768;
    short8 b_f[4][2];
#pragma unroll
    for (int n = 0; n < 4; n++)
#pragma unroll
      for (int ks = 0; ks < 2; ks++)
        b_f[n][ks] = *(const short8*)(Bb + SWZ((wcol + n * 16 + rlo) * 128 + ks * 64 + kgb));
    __builtin_amdgcn_s_setprio(1);
#pragma unroll
    for (int m = 0; m < 8; m++) {
      short8 a0 = *(const short8*)(Ab + SWZ((wrow + m * 16 + rlo) * 128 + kgb));
      short8 a1 = *(const short8*)(Ab + SWZ((wrow + m * 16 + rlo) * 128 + 64 + kgb));
#pragma unroll
      for (int n = 0; n < 4; n++) {
        acc[m][n] = __builtin_amdgcn_mfma_f32_16x16x32_bf16(a0, b_f[n][0], acc[m][n], 0, 0, 0);
        acc[m][n] = __builtin_amdgcn_mfma_f32_16x16x32_bf16(a1, b_f[n][1], acc[m][n], 0, 0, 0);
      }
    }
    __builtin_amdgcn_s_setprio(0);
    asm volatile("s_barrier" ::: "memory");  // reads done; buf reusable
  }
#undef STAGE_TILE

  // epilogue: norms2 = max(x2 + w2 - 2*xw, 0)
  float w2v[4];
#pragma unroll
  for (int n = 0; n < 4; n++) w2v[n] = w2[n0 + wcol + n * 16 + rlo];
#pragma unroll
  for (int m = 0; m < 8; m++) {
#pragma unroll
    for (int j = 0; j < 4; j++) {
      int row = m0 + wrow + m * 16 + (lane >> 4) * 4 + j;
      float xr = x2[row];
      float* orow = out + (size_t)row * KDIM;
#pragma unroll
      for (int n = 0; n < 4; n++) {
        int col = n0 + wcol + n * 16 + rlo;
        float v = xr + w2v[n] - 2.0f * acc[m][n][j];
        orow[col] = v < 0.f ? 0.f : v;
      }
    }
  }
}

// ---------- fallback fp32 GEMM (exact), used only if ws too small ----------
__global__ __launch_bounds__(256) void k_fb(const float* __restrict__ x,
                                            const float* __restrict__ w,
                                            float* __restrict__ out) {
  __shared__ float xs[16][65];
  __shared__ float wsm[16][65];
  const int t = threadIdx.x;
  const int n0 = blockIdx.x * 64, k0 = blockIdx.y * 64;
  const int tx = t & 15, ty = t >> 4;
  float acc[4][4];
#pragma unroll
  for (int a = 0; a < 4; a++)
#pragma unroll
    for (int b = 0; b < 4; b++) acc[a][b] = 0.f;
  for (int c0 = 0; c0 < CDIM; c0 += 16) {
#pragma unroll
    for (int i = 0; i < 4; i++) {
      int e = i * 256 + t;
      int nl = e >> 4, cl = e & 15;
      xs[cl][nl] = x[(size_t)(n0 + nl) * CDIM + c0 + cl];
    }
#pragma unroll
    for (int i = 0; i < 4; i++) {
      int e = i * 256 + t;
      int cl = e >> 6, kl = e & 63;
      wsm[cl][kl] = w[(size_t)(c0 + cl) * KDIM + k0 + kl];
    }
    __syncthreads();
#pragma unroll
    for (int c = 0; c < 16; c++)
#pragma unroll
      for (int a = 0; a < 4; a++) {
        float xa = xs[c][ty * 4 + a];
#pragma unroll
        for (int b = 0; b < 4; b++) {
          float d = wsm[c][tx * 4 + b] - xa;
          acc[a][b] += d * d;
        }
      }
    __syncthreads();
  }
#pragma unroll
  for (int a = 0; a < 4; a++)
#pragma unroll
    for (int b = 0; b < 4; b++)
      out[(size_t)(n0 + ty * 4 + a) * KDIM + k0 + tx * 4 + b] = acc[a][b];
}

// ---------- per-row: min -> candidates -> exact refine -> RBF scale ----------
__global__ __launch_bounds__(256) void k_row(
    float* __restrict__ out, const float* __restrict__ stdp,
    const float* __restrict__ x, const unsigned short* __restrict__ whT,
    const unsigned short* __restrict__ wlT, const float* __restrict__ w2) {
  const int n = blockIdx.x, t = threadIdx.x;
  __shared__ alignas(16) float er[SIDE];
  __shared__ alignas(16) float ec[SIDE];
  __shared__ float rv[4];
  __shared__ float s_red[4];
  __shared__ int cand[128];
  __shared__ int s_ncand;
  __shared__ int s_bmu;
  __shared__ float s_inv;
  float* row = out + (size_t)n * KDIM;

  // pass 1: block-min of approximate scores
  float bv = 3.4e38f;
#pragma unroll 4
  for (int i = 0; i < 16; i++) {
    float4 v = *(const float4*)(row + (t + i * 256) * 4);
    bv = fminf(fminf(fminf(bv, v.x), fminf(v.y, v.z)), v.w);
  }
#pragma unroll
  for (int off = 32; off > 0; off >>= 1) bv = fminf(bv, __shfl_down(bv, off));
  if ((t & 63) == 0) rv[t >> 6] = bv;
  if (t == 0) s_ncand = 0;
  __syncthreads();
  const float thr = fminf(fminf(rv[0], rv[1]), fminf(rv[2], rv[3])) + 0.05f;

  // pass 2: collect candidate indices within the safety window (L2-resident)
#pragma unroll 4
  for (int i = 0; i < 16; i++) {
    int k = (t + i * 256) * 4;
    float4 v = *(const float4*)(row + k);
    if (v.x <= thr) { int j = atomicAdd(&s_ncand, 1); if (j < 128) cand[j] = k; }
    if (v.y <= thr) { int j = atomicAdd(&s_ncand, 1); if (j < 128) cand[j] = k + 1; }
    if (v.z <= thr) { int j = atomicAdd(&s_ncand, 1); if (j < 128) cand[j] = k + 2; }
    if (v.w <= thr) { int j = atomicAdd(&s_ncand, 1); if (j < 128) cand[j] = k + 3; }
  }
  __syncthreads();
  int nc = s_ncand < 128 ? s_ncand : 128;

  // refine: exact score = w2[k] - 2 * dot(x_f32, wh+wl) per candidate
  float best = 3.4e38f;
  int bestk = 0x7fffffff;
  const float* xr = x + (size_t)n * CDIM;
  for (int j = 0; j < nc; j++) {
    const int k = cand[j];
    const unsigned short* wh = whT + (size_t)k * CDIM;
    const unsigned short* wl = wlT + (size_t)k * CDIM;
    float s = 0.f;
#pragma unroll
    for (int ii = 0; ii < 2; ii++) {
      int c = (ii * 256 + t) * 8;
      short8 h8 = *(const short8*)(wh + c);
      short8 l8 = *(const short8*)(wl + c);
      float4 xa = *(const float4*)(xr + c);
      float4 xb = *(const float4*)(xr + c + 4);
      s += xa.x * (bf2f((unsigned short)h8[0]) + bf2f((unsigned short)l8[0]));
      s += xa.y * (bf2f((unsigned short)h8[1]) + bf2f((unsigned short)l8[1]));
      s += xa.z * (bf2f((unsigned short)h8[2]) + bf2f((unsigned short)l8[2]));
      s += xa.w * (bf2f((unsigned short)h8[3]) + bf2f((unsigned short)l8[3]));
      s += xb.x * (bf2f((unsigned short)h8[4]) + bf2f((unsigned short)l8[4]));
      s += xb.y * (bf2f((unsigned short)h8[5]) + bf2f((unsigned short)l8[5]));
      s += xb.z * (bf2f((unsigned short)h8[6]) + bf2f((unsigned short)l8[6]));
      s += xb.w * (bf2f((unsigned short)h8[7]) + bf2f((unsigned short)l8[7]));
    }
#pragma unroll
    for (int off = 32; off > 0; off >>= 1) s += __shfl_down(s, off);
    if ((t & 63) == 0) s_red[t >> 6] = s;
    __syncthreads();
    if (t == 0) {
      float dot = s_red[0] + s_red[1] + s_red[2] + s_red[3];
      float sc = w2[k] - 2.0f * dot;
      if (sc < best || (sc == best && k < bestk)) { best = sc; bestk = k; }
    }
    __syncthreads();
  }
  if (t == 0) s_bmu = bestk;
  __syncthreads();

  const int bmu = s_bmu;
  const float sd = stdp[0];
  const float inv2s2 = -0.5f / (sd * sd);
  const float rr = (float)(bmu >> 7), ccol = (float)(bmu & 127);
  if (t < 128) {
    float d = (float)t - rr;
    er[t] = expf(d * d * inv2s2);
  } else {
    int j = t - 128;
    float d = (float)j - ccol;
    ec[j] = expf(d * d * inv2s2);
  }
  __syncthreads();
  if (t == 0) {
    float Sr = 0.f, Sc = 0.f;
    for (int i = 0; i < SIDE; i++) { Sr += er[i]; Sc += ec[i]; }
    s_inv = 1.0f / (Sr * Sc);
  }
  __syncthreads();
  const float inv = s_inv;
#pragma unroll 4
  for (int i = 0; i < 16; i++) {
    int k = (t + i * 256) * 4;
    float4 v = *(const float4*)(row + k);
    float e_r = er[k >> 7] * inv;
    const float4 e4 = *(const float4*)(&ec[k & 127]);
    v.x *= e_r * e4.x;
    v.y *= e_r * e4.y;
    v.z *= e_r * e4.z;
    v.w *= e_r * e4.w;
    *(float4*)(row + k) = v;
  }
}

// ---------- fallback per-row (exact norms2 from k_fb) ----------
__global__ __launch_bounds__(256) void k_row_fb(float* __restrict__ out,
                                                const float* __restrict__ stdp) {
  const int n = blockIdx.x, t = threadIdx.x;
  __shared__ alignas(16) float er[SIDE];
  __shared__ alignas(16) float ec[SIDE];
  __shared__ float rv[4];
  __shared__ int ri[4];
  __shared__ float s_inv;
  __shared__ int s_bmu;
  float* row = out + (size_t)n * KDIM;

  float bv = 3.4e38f;
  int bi = 0;
#pragma unroll 4
  for (int i = 0; i < 16; i++) {
    int k = (t + i * 256) * 4;
    float4 v = *(const float4*)(row + k);
    if (v.x < bv) { bv = v.x; bi = k; }
    if (v.y < bv) { bv = v.y; bi = k + 1; }
    if (v.z < bv) { bv = v.z; bi = k + 2; }
    if (v.w < bv) { bv = v.w; bi = k + 3; }
  }
#pragma unroll
  for (int off = 32; off > 0; off >>= 1) {
    float ov = __shfl_down(bv, off);
    int oi = __shfl_down(bi, off);
    if (ov < bv || (ov == bv && oi < bi)) { bv = ov; bi = oi; }
  }
  if ((t & 63) == 0) { rv[t >> 6] = bv; ri[t >> 6] = bi; }
  __syncthreads();
  if (t == 0) {
    for (int i = 1; i < 4; i++)
      if (rv[i] < bv || (rv[i] == bv && ri[i] < bi)) { bv = rv[i]; bi = ri[i]; }
    s_bmu = bi;
  }
  __syncthreads();
  const int bmu = s_bmu;
  const float sd = stdp[0];
  const float inv2s2 = -0.5f / (sd * sd);
  const float rr = (float)(bmu >> 7), ccol = (float)(bmu & 127);
  if (t < 128) {
    float d = (float)t - rr;
    er[t] = expf(d * d * inv2s2);
  } else {
    int j = t - 128;
    float d = (float)j - ccol;
    ec[j] = expf(d * d * inv2s2);
  }
  __syncthreads();
  if (t == 0) {
    float Sr = 0.f, Sc = 0.f;
    for (int i = 0; i < SIDE; i++) { Sr += er[i]; Sc += ec[i]; }
    s_inv = 1.0f / (Sr * Sc);
  }
  __syncthreads();
  const float inv = s_inv;
#pragma unroll 4
  for (int i = 0; i < 16; i++) {
    int k = (t + i * 256) * 4;
    float4 v = *(const float4*)(row + k);
    float e_r = er[k >> 7] * inv;
    const float4 e4 = *(const float4*)(&ec[k & 127]);
    v.x *= e_r * e4.x;
    v.y *= e_r * e4.y;
    v.z *= e_r * e4.z;
    v.w *= e_r * e4.w;
    *(float4*)(row + k) = v;
  }
}

extern "C" void kernel_launch(void* const* d_in, const int* in_sizes, int n_in,
                              void* d_out, int out_size, void* d_ws, size_t ws_size,
                              hipStream_t stream) {
  (void)in_sizes; (void)n_in; (void)out_size;
  const float* x = (const float*)d_in[0];
  const float* w = (const float*)d_in[1];
  const float* stdp = (const float*)d_in[2];
  float* out = (float*)d_out;

  const size_t sz_wT = (size_t)KDIM * CDIM * sizeof(unsigned short);  // 128 MiB each
  const size_t sz_x  = (size_t)NROWS * CDIM * sizeof(unsigned short); // 8 MiB
  const size_t need = 2 * sz_wT + sz_x + (size_t)NROWS * 4 + (size_t)KDIM * 4;

  if (ws_size >= need) {
    char* p = (char*)d_ws;
    unsigned short* whT = (unsigned short*)p; p += sz_wT;
    unsigned short* wlT = (unsigned short*)p; p += sz_wT;
    unsigned short* xh  = (unsigned short*)p; p += sz_x;
    float* x2 = (float*)p; p += (size_t)NROWS * 4;
    float* w2 = (float*)p;

    // allow 128 KB dynamic LDS for k_gemm (host-side, idempotent, capture-safe)
    static int lds_ok = -1;
    if (lds_ok < 0)
      lds_ok = (int)hipFuncSetAttribute((const void*)k_gemm,
                                        hipFuncAttributeMaxDynamicSharedMemorySize,
                                        131072);

    k_prep<<<NROWS, 256, 0, stream>>>(x, xh, x2, w2);
    k_wconv<<<dim3(KDIM / 64, CDIM / 64), 256, 0, stream>>>(w, whT, wlT, w2);
    k_gemm<<<256, 512, 131072, stream>>>(xh, whT, x2, w2, out);
    k_row<<<NROWS, 256, 0, stream>>>(out, stdp, x, whT, wlT, w2);
  } else {
    k_fb<<<dim3(NROWS / 64, KDIM / 64), 256, 0, stream>>>(x, w, out);
    k_row_fb<<<NROWS, 256, 0, stream>>>(out, stdp);
  }
}

// Round 11
// 290.344 us; speedup vs baseline: 1.3179x; 1.0435x over previous
//
#include <hip/hip_runtime.h>
#include <stdint.h>

#define NROWS 1024
#define CDIM  4096
#define KDIM  16384
#define SIDE  128

typedef __attribute__((ext_vector_type(8))) short short8;
typedef __attribute__((ext_vector_type(4))) float f32x4;

static __device__ __forceinline__ unsigned short f2bf(float f) {
  unsigned u = __float_as_uint(f);
  u += 0x7fffu + ((u >> 16) & 1u);   // round-to-nearest-even
  return (unsigned short)(u >> 16);
}
static __device__ __forceinline__ float bf2f(unsigned short h) {
  return __uint_as_float(((unsigned)h) << 16);
}

#define GLOAD_LDS16(g, l)                                                     \
  __builtin_amdgcn_global_load_lds(                                           \
      (const __attribute__((address_space(1))) void*)(g),                     \
      (__attribute__((address_space(3))) void*)(l), 16, 0, 0)

// 128B-row XOR-swizzle (PROVEN 0 conflicts R3/R4/R9/R10 with the 16-row x
// 4-kgroup fragment pattern): 16B-chunk bits [6:4] ^= row bits [9:7].
// Involution; 16B-aligned; row-preserving.
#define SWZ(o) ((o) ^ (((o) >> 3) & 0x70))

// ---------- prep: xh = bf16(x), x2[n] = sum x^2, w2 = 0 (merged) ----------
__global__ __launch_bounds__(256) void k_prep(const float* __restrict__ x,
                                              unsigned short* __restrict__ xh,
                                              float* __restrict__ x2,
                                              float* __restrict__ w2) {
  const int n = blockIdx.x, t = threadIdx.x;
  __shared__ float rv[4];
  if (n < 64) w2[n * 256 + t] = 0.f;  // zero w2 (16384 floats over 64 blocks)
  const float* row = x + (size_t)n * CDIM;
  unsigned short* xrow = xh + (size_t)n * CDIM;
  float s = 0.f;
#pragma unroll
  for (int i = 0; i < 4; i++) {
    int e = (t + i * 256) * 4;
    float4 v = *(const float4*)(row + e);
    ushort4 hv;
    hv.x = f2bf(v.x); hv.y = f2bf(v.y); hv.z = f2bf(v.z); hv.w = f2bf(v.w);
    *(ushort4*)(xrow + e) = hv;
    s += v.x * v.x + v.y * v.y + v.z * v.z + v.w * v.w;
  }
#pragma unroll
  for (int off = 32; off > 0; off >>= 1) s += __shfl_down(s, off);
  if ((t & 63) == 0) rv[t >> 6] = s;
  __syncthreads();
  if (t == 0) x2[n] = rv[0] + rv[1] + rv[2] + rv[3];
}

// ---------- weights: f32 [c][k] -> bf16 hi/lo transposed [k][c]; fused w2 ----
__global__ __launch_bounds__(256) void k_wconv(const float* __restrict__ w,
                                               unsigned short* __restrict__ whT,
                                               unsigned short* __restrict__ wlT,
                                               float* __restrict__ w2) {
  __shared__ float T[64][65];
  const int k0 = blockIdx.x * 64, c0 = blockIdx.y * 64;
  const int t = threadIdx.x;
#pragma unroll
  for (int i = 0; i < 4; i++) {
    int e = i * 1024 + t * 4;
    int cr = e >> 6, kc = e & 63;
    float4 v = *(const float4*)(w + (size_t)(c0 + cr) * KDIM + k0 + kc);
    T[cr][kc] = v.x; T[cr][kc + 1] = v.y; T[cr][kc + 2] = v.z; T[cr][kc + 3] = v.w;
  }
  __syncthreads();
#pragma unroll
  for (int i = 0; i < 4; i++) {
    int e = i * 1024 + t * 4;
    int kr = e >> 6, cc = e & 63;
    ushort4 hv, lv;
    float f0 = T[cc + 0][kr], f1 = T[cc + 1][kr];
    float f2 = T[cc + 2][kr], f3 = T[cc + 3][kr];
    hv.x = f2bf(f0); lv.x = f2bf(f0 - bf2f(hv.x));
    hv.y = f2bf(f1); lv.y = f2bf(f1 - bf2f(hv.y));
    hv.z = f2bf(f2); lv.z = f2bf(f2 - bf2f(hv.z));
    hv.w = f2bf(f3); lv.w = f2bf(f3 - bf2f(hv.w));
    size_t off = (size_t)(k0 + kr) * CDIM + c0 + cc;
    *(ushort4*)(whT + off) = hv;
    *(ushort4*)(wlT + off) = lv;
    float s = f0 * f0 + f1 * f1 + f2 * f2 + f3 * f3;
#pragma unroll
    for (int off2 = 8; off2 > 0; off2 >>= 1) s += __shfl_down(s, off2);
    if ((t & 15) == 0) atomicAdd(&w2[k0 + kr], s);
  }
}

// ---------- main MFMA GEMM: BM=BN=256, BK=64, 8 waves (2M x 4N) ----------
// R10-proven body with ONE change: B (whT, the cold stream) is now
// TRIPLE-buffered (staged 2 tiles ahead) while A (xh, L2-hot) stays double-
// buffered. LDS = 2x32K (A) + 3x32K (B) = 160 KB. Per iter: stage A(t+1),
// B(t+2), then vmcnt(12) = newest {B(t+2),A(t+1),B(t+1)} may fly; A(t),B(t)
// guaranteed landed. Tail stages clamp to tile 63 (idempotent data into
// already-consumed slots). 16x16x32 MFMA, SWZ (0-conflict), setprio, XCD map.
__global__ __launch_bounds__(512, 2) void k_gemm(
    const unsigned short* __restrict__ xh,
    const unsigned short* __restrict__ whT,
    const float* __restrict__ x2, const float* __restrict__ w2,
    float* __restrict__ out) {
  extern __shared__ char smem[];  // 163840 B: A slots 0,32K; B slots 64K,96K,128K
  const int t = threadIdx.x;
  const int b = blockIdx.x;
  const int L = (b & 7) * 32 + (b >> 3);   // XCD-bijective (256 wgs)
  const int m0 = (L & 3) * 256, n0 = (L >> 2) * 256;
  const int lane = t & 63, wid = t >> 6;
  const int wrow = (wid >> 2) * 128;   // wave M-half: 0 or 128
  const int wcol = (wid & 3) * 64;     // wave N-quarter
  const int rlo = lane & 15;
  const int kgb = (lane >> 4) * 16;    // k-group byte offset in a K=32 slice

  // staging geometry (rule #21): linear LDS chunk o_lin holds logical chunk
  // SWZ(o_lin) of the 256x64 operand tile (32 KB = 4 chunks x 512 thr x 16B).
  int rowS[4], cbS[4];
  uint32_t loffS[4];
#pragma unroll
  for (int i = 0; i < 4; i++) {
    int o_lin = (i * 512 + t) * 16;
    int o_log = SWZ(o_lin);
    rowS[i] = o_log >> 7;          // 0..255
    cbS[i] = (o_log & 127) >> 1;   // element col 0..63
    loffS[i] = i * 8192 + wid * 1024;  // wave-uniform linear LDS base
  }

  f32x4 acc[8][4];
#pragma unroll
  for (int m = 0; m < 8; m++)
#pragma unroll
    for (int n = 0; n < 4; n++) acc[m][n] = (f32x4){0.f, 0.f, 0.f, 0.f};

#define STAGE_A(tt)                                                           \
  {                                                                           \
    const int tc_ = (tt) < 63 ? (tt) : 63;                                    \
    const int c0s = tc_ * 64;                                                 \
    char* const dst = smem + (((tt) & 1) * 32768);                            \
    _Pragma("unroll")                                                         \
    for (int i = 0; i < 4; i++) {                                             \
      size_t ga = (size_t)(m0 + rowS[i]) * CDIM + c0s + cbS[i];               \
      GLOAD_LDS16(xh + ga, dst + loffS[i]);                                   \
    }                                                                         \
  }
#define STAGE_B(tt)                                                           \
  {                                                                           \
    const int tc_ = (tt) < 63 ? (tt) : 63;                                    \
    const int c0s = tc_ * 64;                                                 \
    char* const dst = smem + 65536 + (((tt) % 3) * 32768);                    \
    _Pragma("unroll")                                                         \
    for (int i = 0; i < 4; i++) {                                             \
      size_t gb = (size_t)(n0 + rowS[i]) * CDIM + c0s + cbS[i];               \
      GLOAD_LDS16(whT + gb, dst + 32768 + loffS[i] - 32768);                  \
    }                                                                         \
  }

  // prologue: A(0), B(0), B(1); wait for A(0)+B(0) (B(1) stays in flight)
  STAGE_A(0);
  STAGE_B(0);
  STAGE_B(1);
  asm volatile("s_waitcnt vmcnt(4)" ::: "memory");
  asm volatile("s_barrier" ::: "memory");

  for (int tl = 0; tl < 64; ++tl) {
    STAGE_A(tl + 1);   // slot (tl+1)&1 (its reads finished at iter tl-1)
    STAGE_B(tl + 2);   // slot (tl+2)%3 (its reads finished at iter tl-1)
    asm volatile("s_waitcnt vmcnt(12)" ::: "memory");  // A(tl),B(tl) landed
    asm volatile("s_barrier" ::: "memory");            // ...for all waves

    const char* const Ab = smem + (tl & 1) * 32768;
    const char* const Bb = smem + 65536 + (tl % 3) * 32768;
    short8 b_f[4][2];
#pragma unroll
    for (int n = 0; n < 4; n++)
#pragma unroll
      for (int ks = 0; ks < 2; ks++)
        b_f[n][ks] = *(const short8*)(Bb + SWZ((wcol + n * 16 + rlo) * 128 + ks * 64 + kgb));
    __builtin_amdgcn_s_setprio(1);
#pragma unroll
    for (int m = 0; m < 8; m++) {
      short8 a0 = *(const short8*)(Ab + SWZ((wrow + m * 16 + rlo) * 128 + kgb));
      short8 a1 = *(const short8*)(Ab + SWZ((wrow + m * 16 + rlo) * 128 + 64 + kgb));
#pragma unroll
      for (int n = 0; n < 4; n++) {
        acc[m][n] = __builtin_amdgcn_mfma_f32_16x16x32_bf16(a0, b_f[n][0], acc[m][n], 0, 0, 0);
        acc[m][n] = __builtin_amdgcn_mfma_f32_16x16x32_bf16(a1, b_f[n][1], acc[m][n], 0, 0, 0);
      }
    }
    __builtin_amdgcn_s_setprio(0);
    asm volatile("s_barrier" ::: "memory");  // reads done; slots reusable
  }
#undef STAGE_A
#undef STAGE_B
  asm volatile("s_waitcnt vmcnt(0)" ::: "memory");  // drain dup tail stages

  // epilogue: norms2 = max(x2 + w2 - 2*xw, 0)
  float w2v[4];
#pragma unroll
  for (int n = 0; n < 4; n++) w2v[n] = w2[n0 + wcol + n * 16 + rlo];
#pragma unroll
  for (int m = 0; m < 8; m++) {
#pragma unroll
    for (int j = 0; j < 4; j++) {
      int row = m0 + wrow + m * 16 + (lane >> 4) * 4 + j;
      float xr = x2[row];
      float* orow = out + (size_t)row * KDIM;
#pragma unroll
      for (int n = 0; n < 4; n++) {
        int col = n0 + wcol + n * 16 + rlo;
        float v = xr + w2v[n] - 2.0f * acc[m][n][j];
        orow[col] = v < 0.f ? 0.f : v;
      }
    }
  }
}

// ---------- fallback fp32 GEMM (exact), used only if ws too small ----------
__global__ __launch_bounds__(256) void k_fb(const float* __restrict__ x,
                                            const float* __restrict__ w,
                                            float* __restrict__ out) {
  __shared__ float xs[16][65];
  __shared__ float wsm[16][65];
  const int t = threadIdx.x;
  const int n0 = blockIdx.x * 64, k0 = blockIdx.y * 64;
  const int tx = t & 15, ty = t >> 4;
  float acc[4][4];
#pragma unroll
  for (int a = 0; a < 4; a++)
#pragma unroll
    for (int b = 0; b < 4; b++) acc[a][b] = 0.f;
  for (int c0 = 0; c0 < CDIM; c0 += 16) {
#pragma unroll
    for (int i = 0; i < 4; i++) {
      int e = i * 256 + t;
      int nl = e >> 4, cl = e & 15;
      xs[cl][nl] = x[(size_t)(n0 + nl) * CDIM + c0 + cl];
    }
#pragma unroll
    for (int i = 0; i < 4; i++) {
      int e = i * 256 + t;
      int cl = e >> 6, kl = e & 63;
      wsm[cl][kl] = w[(size_t)(c0 + cl) * KDIM + k0 + kl];
    }
    __syncthreads();
#pragma unroll
    for (int c = 0; c < 16; c++)
#pragma unroll
      for (int a = 0; a < 4; a++) {
        float xa = xs[c][ty * 4 + a];
#pragma unroll
        for (int b = 0; b < 4; b++) {
          float d = wsm[c][tx * 4 + b] - xa;
          acc[a][b] += d * d;
        }
      }
    __syncthreads();
  }
#pragma unroll
  for (int a = 0; a < 4; a++)
#pragma unroll
    for (int b = 0; b < 4; b++)
      out[(size_t)(n0 + ty * 4 + a) * KDIM + k0 + tx * 4 + b] = acc[a][b];
}

// ---------- per-row: min -> candidates (from regs) -> refine -> RBF scale ----
__global__ __launch_bounds__(256) void k_row(
    float* __restrict__ out, const float* __restrict__ stdp,
    const float* __restrict__ x, const unsigned short* __restrict__ whT,
    const unsigned short* __restrict__ wlT, const float* __restrict__ w2) {
  const int n = blockIdx.x, t = threadIdx.x;
  __shared__ alignas(16) float er[SIDE];
  __shared__ alignas(16) float ec[SIDE];
  __shared__ float rv[4];
  __shared__ float s_red[4];
  __shared__ int cand[128];
  __shared__ int s_ncand;
  __shared__ int s_bmu;
  __shared__ float s_inv;
  float* row = out + (size_t)n * KDIM;

  // pass 1: load row into registers once; block-min
  float4 vals[16];
  float bv = 3.4e38f;
#pragma unroll
  for (int i = 0; i < 16; i++) {
    vals[i] = *(const float4*)(row + (t + i * 256) * 4);
    bv = fminf(fminf(fminf(bv, vals[i].x), fminf(vals[i].y, vals[i].z)), vals[i].w);
  }
#pragma unroll
  for (int off = 32; off > 0; off >>= 1) bv = fminf(bv, __shfl_down(bv, off));
  if ((t & 63) == 0) rv[t >> 6] = bv;
  if (t == 0) s_ncand = 0;
  __syncthreads();
  const float thr = fminf(fminf(rv[0], rv[1]), fminf(rv[2], rv[3])) + 0.05f;

  // pass 2: collect candidates from REGISTERS (no memory re-read)
#pragma unroll
  for (int i = 0; i < 16; i++) {
    int k = (t + i * 256) * 4;
    if (vals[i].x <= thr) { int j = atomicAdd(&s_ncand, 1); if (j < 128) cand[j] = k; }
    if (vals[i].y <= thr) { int j = atomicAdd(&s_ncand, 1); if (j < 128) cand[j] = k + 1; }
    if (vals[i].z <= thr) { int j = atomicAdd(&s_ncand, 1); if (j < 128) cand[j] = k + 2; }
    if (vals[i].w <= thr) { int j = atomicAdd(&s_ncand, 1); if (j < 128) cand[j] = k + 3; }
  }
  __syncthreads();
  int nc = s_ncand < 128 ? s_ncand : 128;

  // refine: exact score = w2[k] - 2 * dot(x_f32, wh+wl) per candidate
  float best = 3.4e38f;
  int bestk = 0x7fffffff;
  const float* xr = x + (size_t)n * CDIM;
  for (int j = 0; j < nc; j++) {
    const int k = cand[j];
    const unsigned short* wh = whT + (size_t)k * CDIM;
    const unsigned short* wl = wlT + (size_t)k * CDIM;
    float s = 0.f;
#pragma unroll
    for (int ii = 0; ii < 2; ii++) {
      int c = (ii * 256 + t) * 8;
      short8 h8 = *(const short8*)(wh + c);
      short8 l8 = *(const short8*)(wl + c);
      float4 xa = *(const float4*)(xr + c);
      float4 xb = *(const float4*)(xr + c + 4);
      s += xa.x * (bf2f((unsigned short)h8[0]) + bf2f((unsigned short)l8[0]));
      s += xa.y * (bf2f((unsigned short)h8[1]) + bf2f((unsigned short)l8[1]));
      s += xa.z * (bf2f((unsigned short)h8[2]) + bf2f((unsigned short)l8[2]));
      s += xa.w * (bf2f((unsigned short)h8[3]) + bf2f((unsigned short)l8[3]));
      s += xb.x * (bf2f((unsigned short)h8[4]) + bf2f((unsigned short)l8[4]));
      s += xb.y * (bf2f((unsigned short)h8[5]) + bf2f((unsigned short)l8[5]));
      s += xb.z * (bf2f((unsigned short)h8[6]) + bf2f((unsigned short)l8[6]));
      s += xb.w * (bf2f((unsigned short)h8[7]) + bf2f((unsigned short)l8[7]));
    }
#pragma unroll
    for (int off = 32; off > 0; off >>= 1) s += __shfl_down(s, off);
    if ((t & 63) == 0) s_red[t >> 6] = s;
    __syncthreads();
    if (t == 0) {
      float dot = s_red[0] + s_red[1] + s_red[2] + s_red[3];
      float sc = w2[k] - 2.0f * dot;
      if (sc < best || (sc == best && k < bestk)) { best = sc; bestk = k; }
    }
    __syncthreads();
  }
  if (t == 0) s_bmu = bestk;
  __syncthreads();

  const int bmu = s_bmu;
  const float sd = stdp[0];
  const float inv2s2 = -0.5f / (sd * sd);
  const float rr = (float)(bmu >> 7), ccol = (float)(bmu & 127);
  if (t < 128) {
    float d = (float)t - rr;
    er[t] = expf(d * d * inv2s2);
  } else {
    int j = t - 128;
    float d = (float)j - ccol;
    ec[j] = expf(d * d * inv2s2);
  }
  __syncthreads();
  if (t == 0) {
    float Sr = 0.f, Sc = 0.f;
    for (int i = 0; i < SIDE; i++) { Sr += er[i]; Sc += ec[i]; }
    s_inv = 1.0f / (Sr * Sc);
  }
  __syncthreads();
  const float inv = s_inv;
#pragma unroll
  for (int i = 0; i < 16; i++) {
    int k = (t + i * 256) * 4;
    float4 v = vals[i];
    float e_r = er[k >> 7] * inv;
    const float4 e4 = *(const float4*)(&ec[k & 127]);
    v.x *= e_r * e4.x;
    v.y *= e_r * e4.y;
    v.z *= e_r * e4.z;
    v.w *= e_r * e4.w;
    *(float4*)(row + k) = v;
  }
}

// ---------- fallback per-row (exact norms2 from k_fb) ----------
__global__ __launch_bounds__(256) void k_row_fb(float* __restrict__ out,
                                                const float* __restrict__ stdp) {
  const int n = blockIdx.x, t = threadIdx.x;
  __shared__ alignas(16) float er[SIDE];
  __shared__ alignas(16) float ec[SIDE];
  __shared__ float rv[4];
  __shared__ int ri[4];
  __shared__ float s_inv;
  __shared__ int s_bmu;
  float* row = out + (size_t)n * KDIM;

  float bv = 3.4e38f;
  int bi = 0;
#pragma unroll 4
  for (int i = 0; i < 16; i++) {
    int k = (t + i * 256) * 4;
    float4 v = *(const float4*)(row + k);
    if (v.x < bv) { bv = v.x; bi = k; }
    if (v.y < bv) { bv = v.y; bi = k + 1; }
    if (v.z < bv) { bv = v.z; bi = k + 2; }
    if (v.w < bv) { bv = v.w; bi = k + 3; }
  }
#pragma unroll
  for (int off = 32; off > 0; off >>= 1) {
    float ov = __shfl_down(bv, off);
    int oi = __shfl_down(bi, off);
    if (ov < bv || (ov == bv && oi < bi)) { bv = ov; bi = oi; }
  }
  if ((t & 63) == 0) { rv[t >> 6] = bv; ri[t >> 6] = bi; }
  __syncthreads();
  if (t == 0) {
    for (int i = 1; i < 4; i++)
      if (rv[i] < bv || (rv[i] == bv && ri[i] < bi)) { bv = rv[i]; bi = ri[i]; }
    s_bmu = bi;
  }
  __syncthreads();
  const int bmu = s_bmu;
  const float sd = stdp[0];
  const float inv2s2 = -0.5f / (sd * sd);
  const float rr = (float)(bmu >> 7), ccol = (float)(bmu & 127);
  if (t < 128) {
    float d = (float)t - rr;
    er[t] = expf(d * d * inv2s2);
  } else {
    int j = t - 128;
    float d = (float)j - ccol;
    ec[j] = expf(d * d * inv2s2);
  }
  __syncthreads();
  if (t == 0) {
    float Sr = 0.f, Sc = 0.f;
    for (int i = 0; i < SIDE; i++) { Sr += er[i]; Sc += ec[i]; }
    s_inv = 1.0f / (Sr * Sc);
  }
  __syncthreads();
  const float inv = s_inv;
#pragma unroll 4
  for (int i = 0; i < 16; i++) {
    int k = (t + i * 256) * 4;
    float4 v = *(const float4*)(row + k);
    float e_r = er[k >> 7] * inv;
    const float4 e4 = *(const float4*)(&ec[k & 127]);
    v.x *= e_r * e4.x;
    v.y *= e_r * e4.y;
    v.z *= e_r * e4.z;
    v.w *= e_r * e4.w;
    *(float4*)(row + k) = v;
  }
}

extern "C" void kernel_launch(void* const* d_in, const int* in_sizes, int n_in,
                              void* d_out, int out_size, void* d_ws, size_t ws_size,
                              hipStream_t stream) {
  (void)in_sizes; (void)n_in; (void)out_size;
  const float* x = (const float*)d_in[0];
  const float* w = (const float*)d_in[1];
  const float* stdp = (const float*)d_in[2];
  float* out = (float*)d_out;

  const size_t sz_wT = (size_t)KDIM * CDIM * sizeof(unsigned short);  // 128 MiB each
  const size_t sz_x  = (size_t)NROWS * CDIM * sizeof(unsigned short); // 8 MiB
  const size_t need = 2 * sz_wT + sz_x + (size_t)NROWS * 4 + (size_t)KDIM * 4;

  if (ws_size >= need) {
    char* p = (char*)d_ws;
    unsigned short* whT = (unsigned short*)p; p += sz_wT;
    unsigned short* wlT = (unsigned short*)p; p += sz_wT;
    unsigned short* xh  = (unsigned short*)p; p += sz_x;
    float* x2 = (float*)p; p += (size_t)NROWS * 4;
    float* w2 = (float*)p;

    // allow 160 KB dynamic LDS for k_gemm (host-side, idempotent, capture-safe)
    static int lds_ok = -1;
    if (lds_ok < 0)
      lds_ok = (int)hipFuncSetAttribute((const void*)k_gemm,
                                        hipFuncAttributeMaxDynamicSharedMemorySize,
                                        163840);

    k_prep<<<NROWS, 256, 0, stream>>>(x, xh, x2, w2);
    k_wconv<<<dim3(KDIM / 64, CDIM / 64), 256, 0, stream>>>(w, whT, wlT, w2);
    k_gemm<<<256, 512, 163840, stream>>>(xh, whT, x2, w2, out);
    k_row<<<NROWS, 256, 0, stream>>>(out, stdp, x, whT, wlT, w2);
  } else {
    k_fb<<<dim3(NROWS / 64, KDIM / 64), 256, 0, stream>>>(x, w, out);
    k_row_fb<<<NROWS, 256, 0, stream>>>(out, stdp);
  }
}

// Round 12
// 280.549 us; speedup vs baseline: 1.3639x; 1.0349x over previous
//
#include <hip/hip_runtime.h>
#include <stdint.h>

#define NROWS 1024
#define CDIM  4096
#define KDIM  16384
#define SIDE  128

typedef __attribute__((ext_vector_type(8))) short short8;
typedef __attribute__((ext_vector_type(4))) float f32x4;

static __device__ __forceinline__ unsigned short f2bf(float f) {
  unsigned u = __float_as_uint(f);
  u += 0x7fffu + ((u >> 16) & 1u);   // round-to-nearest-even
  return (unsigned short)(u >> 16);
}
static __device__ __forceinline__ float bf2f(unsigned short h) {
  return __uint_as_float(((unsigned)h) << 16);
}

#define GLOAD_LDS16(g, l)                                                     \
  __builtin_amdgcn_global_load_lds(                                           \
      (const __attribute__((address_space(1))) void*)(g),                     \
      (__attribute__((address_space(3))) void*)(l), 16, 0, 0)

// 128B-row XOR-swizzle (PROVEN 0 conflicts R3/R4/R9/R10/R11 with the 16-row x
// 4-kgroup fragment pattern): 16B-chunk bits [6:4] ^= row bits [9:7].
// Involution; 16B-aligned; row-preserving.
#define SWZ(o) ((o) ^ (((o) >> 3) & 0x70))

// ---------- prep: xh = bf16(x), x2[n] = sum x^2, w2 = 0 (merged) ----------
__global__ __launch_bounds__(256) void k_prep(const float* __restrict__ x,
                                              unsigned short* __restrict__ xh,
                                              float* __restrict__ x2,
                                              float* __restrict__ w2) {
  const int n = blockIdx.x, t = threadIdx.x;
  __shared__ float rv[4];
  if (n < 64) w2[n * 256 + t] = 0.f;  // zero w2 (16384 floats over 64 blocks)
  const float* row = x + (size_t)n * CDIM;
  unsigned short* xrow = xh + (size_t)n * CDIM;
  float s = 0.f;
#pragma unroll
  for (int i = 0; i < 4; i++) {
    int e = (t + i * 256) * 4;
    float4 v = *(const float4*)(row + e);
    ushort4 hv;
    hv.x = f2bf(v.x); hv.y = f2bf(v.y); hv.z = f2bf(v.z); hv.w = f2bf(v.w);
    *(ushort4*)(xrow + e) = hv;
    s += v.x * v.x + v.y * v.y + v.z * v.z + v.w * v.w;
  }
#pragma unroll
  for (int off = 32; off > 0; off >>= 1) s += __shfl_down(s, off);
  if ((t & 63) == 0) rv[t >> 6] = s;
  __syncthreads();
  if (t == 0) x2[n] = rv[0] + rv[1] + rv[2] + rv[3];
}

// ---------- weights: f32 [c][k] -> bf16 hi/lo transposed [k][c]; fused w2 ----
__global__ __launch_bounds__(256) void k_wconv(const float* __restrict__ w,
                                               unsigned short* __restrict__ whT,
                                               unsigned short* __restrict__ wlT,
                                               float* __restrict__ w2) {
  __shared__ float T[64][65];
  const int k0 = blockIdx.x * 64, c0 = blockIdx.y * 64;
  const int t = threadIdx.x;
#pragma unroll
  for (int i = 0; i < 4; i++) {
    int e = i * 1024 + t * 4;
    int cr = e >> 6, kc = e & 63;
    float4 v = *(const float4*)(w + (size_t)(c0 + cr) * KDIM + k0 + kc);
    T[cr][kc] = v.x; T[cr][kc + 1] = v.y; T[cr][kc + 2] = v.z; T[cr][kc + 3] = v.w;
  }
  __syncthreads();
#pragma unroll
  for (int i = 0; i < 4; i++) {
    int e = i * 1024 + t * 4;
    int kr = e >> 6, cc = e & 63;
    ushort4 hv, lv;
    float f0 = T[cc + 0][kr], f1 = T[cc + 1][kr];
    float f2 = T[cc + 2][kr], f3 = T[cc + 3][kr];
    hv.x = f2bf(f0); lv.x = f2bf(f0 - bf2f(hv.x));
    hv.y = f2bf(f1); lv.y = f2bf(f1 - bf2f(hv.y));
    hv.z = f2bf(f2); lv.z = f2bf(f2 - bf2f(hv.z));
    hv.w = f2bf(f3); lv.w = f2bf(f3 - bf2f(hv.w));
    size_t off = (size_t)(k0 + kr) * CDIM + c0 + cc;
    *(ushort4*)(whT + off) = hv;
    *(ushort4*)(wlT + off) = lv;
    float s = f0 * f0 + f1 * f1 + f2 * f2 + f3 * f3;
#pragma unroll
    for (int off2 = 8; off2 > 0; off2 >>= 1) s += __shfl_down(s, off2);
    if ((t & 15) == 0) atomicAdd(&w2[k0 + kr], s);
  }
}

// ---------- main MFMA GEMM: BM=BN=256, BK=64, 8 waves (2M x 4N) ----------
// R10-PROVEN body (best measured: 155-157us, MfmaUtil 36%, 0 conflicts):
// 16x16x32 MFMA, whole-tile stage (8 gload_lds), counted vmcnt(8),
// 2 barriers/tile, 128KB dbuf LDS, SWZ, setprio, XCD-bijective mapping.
// R11's B-triple-buffer reverted (regressed +7us: B already L2/L3-warm).
__global__ __launch_bounds__(512, 2) void k_gemm(
    const unsigned short* __restrict__ xh,
    const unsigned short* __restrict__ whT,
    const float* __restrict__ x2, const float* __restrict__ w2,
    float* __restrict__ out) {
  extern __shared__ char smem[];  // 131072 B: dbuf d at d*65536; A +0, B +32768
  const int t = threadIdx.x;
  const int b = blockIdx.x;
  const int L = (b & 7) * 32 + (b >> 3);   // XCD-bijective (256 wgs)
  const int m0 = (L & 3) * 256, n0 = (L >> 2) * 256;
  const int lane = t & 63, wid = t >> 6;
  const int wrow = (wid >> 2) * 128;   // wave M-half: 0 or 128
  const int wcol = (wid & 3) * 64;     // wave N-quarter
  const int rlo = lane & 15;
  const int kgb = (lane >> 4) * 16;    // k-group byte offset in a K=32 slice

  // staging geometry (rule #21): linear LDS chunk o_lin holds logical chunk
  // SWZ(o_lin) of the operand tile.
  int rowS[4], cbS[4];
  uint32_t loffS[4];
#pragma unroll
  for (int i = 0; i < 4; i++) {
    int o_lin = (i * 512 + t) * 16;
    int o_log = SWZ(o_lin);
    rowS[i] = o_log >> 7;          // 0..255
    cbS[i] = (o_log & 127) >> 1;   // element col 0..63
    loffS[i] = i * 8192 + wid * 1024;  // wave-uniform linear LDS base
  }

  f32x4 acc[8][4];
#pragma unroll
  for (int m = 0; m < 8; m++)
#pragma unroll
    for (int n = 0; n < 4; n++) acc[m][n] = (f32x4){0.f, 0.f, 0.f, 0.f};

#define STAGE_TILE(tt, d)                                                     \
  {                                                                           \
    const int c0s = (tt) * 64;                                                \
    char* const dst = smem + (d) * 65536;                                     \
    _Pragma("unroll")                                                         \
    for (int i = 0; i < 4; i++) {                                             \
      size_t ga = (size_t)(m0 + rowS[i]) * CDIM + c0s + cbS[i];               \
      GLOAD_LDS16(xh + ga, dst + loffS[i]);                                   \
    }                                                                         \
    _Pragma("unroll")                                                         \
    for (int i = 0; i < 4; i++) {                                             \
      size_t gb = (size_t)(n0 + rowS[i]) * CDIM + c0s + cbS[i];               \
      GLOAD_LDS16(whT + gb, dst + 32768 + loffS[i]);                          \
    }                                                                         \
  }

  STAGE_TILE(0, 0);  // prologue: 8 loads in flight

  for (int tl = 0; tl < 64; ++tl) {
    const int cur = tl & 1;
    if (tl < 63) {
      STAGE_TILE(tl + 1, cur ^ 1);  // 8 more loads; never drain to 0 (T4)
      asm volatile("s_waitcnt vmcnt(8)" ::: "memory");  // tile tl landed
    } else {
      asm volatile("s_waitcnt vmcnt(0)" ::: "memory");
    }
    asm volatile("s_barrier" ::: "memory");  // all waves' loads landed

    const char* const Ab = smem + cur * 65536;
    const char* const Bb = Ab + 32768;
    short8 b_f[4][2];
#pragma unroll
    for (int n = 0; n < 4; n++)
#pragma unroll
      for (int ks = 0; ks < 2; ks++)
        b_f[n][ks] = *(const short8*)(Bb + SWZ((wcol + n * 16 + rlo) * 128 + ks * 64 + kgb));
    __builtin_amdgcn_s_setprio(1);
#pragma unroll
    for (int m = 0; m < 8; m++) {
      short8 a0 = *(const short8*)(Ab + SWZ((wrow + m * 16 + rlo) * 128 + kgb));
      short8 a1 = *(const short8*)(Ab + SWZ((wrow + m * 16 + rlo) * 128 + 64 + kgb));
#pragma unroll
      for (int n = 0; n < 4; n++) {
        acc[m][n] = __builtin_amdgcn_mfma_f32_16x16x32_bf16(a0, b_f[n][0], acc[m][n], 0, 0, 0);
        acc[m][n] = __builtin_amdgcn_mfma_f32_16x16x32_bf16(a1, b_f[n][1], acc[m][n], 0, 0, 0);
      }
    }
    __builtin_amdgcn_s_setprio(0);
    asm volatile("s_barrier" ::: "memory");  // reads done; buf reusable
  }
#undef STAGE_TILE

  // epilogue: norms2 = max(x2 + w2 - 2*xw, 0)
  float w2v[4];
#pragma unroll
  for (int n = 0; n < 4; n++) w2v[n] = w2[n0 + wcol + n * 16 + rlo];
#pragma unroll
  for (int m = 0; m < 8; m++) {
#pragma unroll
    for (int j = 0; j < 4; j++) {
      int row = m0 + wrow + m * 16 + (lane >> 4) * 4 + j;
      float xr = x2[row];
      float* orow = out + (size_t)row * KDIM;
#pragma unroll
      for (int n = 0; n < 4; n++) {
        int col = n0 + wcol + n * 16 + rlo;
        float v = xr + w2v[n] - 2.0f * acc[m][n][j];
        orow[col] = v < 0.f ? 0.f : v;
      }
    }
  }
}

// ---------- fallback fp32 GEMM (exact), used only if ws too small ----------
__global__ __launch_bounds__(256) void k_fb(const float* __restrict__ x,
                                            const float* __restrict__ w,
                                            float* __restrict__ out) {
  __shared__ float xs[16][65];
  __shared__ float wsm[16][65];
  const int t = threadIdx.x;
  const int n0 = blockIdx.x * 64, k0 = blockIdx.y * 64;
  const int tx = t & 15, ty = t >> 4;
  float acc[4][4];
#pragma unroll
  for (int a = 0; a < 4; a++)
#pragma unroll
    for (int b = 0; b < 4; b++) acc[a][b] = 0.f;
  for (int c0 = 0; c0 < CDIM; c0 += 16) {
#pragma unroll
    for (int i = 0; i < 4; i++) {
      int e = i * 256 + t;
      int nl = e >> 4, cl = e & 15;
      xs[cl][nl] = x[(size_t)(n0 + nl) * CDIM + c0 + cl];
    }
#pragma unroll
    for (int i = 0; i < 4; i++) {
      int e = i * 256 + t;
      int cl = e >> 6, kl = e & 63;
      wsm[cl][kl] = w[(size_t)(c0 + cl) * KDIM + k0 + kl];
    }
    __syncthreads();
#pragma unroll
    for (int c = 0; c < 16; c++)
#pragma unroll
      for (int a = 0; a < 4; a++) {
        float xa = xs[c][ty * 4 + a];
#pragma unroll
        for (int b = 0; b < 4; b++) {
          float d = wsm[c][tx * 4 + b] - xa;
          acc[a][b] += d * d;
        }
      }
    __syncthreads();
  }
#pragma unroll
  for (int a = 0; a < 4; a++)
#pragma unroll
    for (int b = 0; b < 4; b++)
      out[(size_t)(n0 + ty * 4 + a) * KDIM + k0 + tx * 4 + b] = acc[a][b];
}

// ---------- per-row: min -> candidates (from regs) -> refine -> RBF scale ----
__global__ __launch_bounds__(256) void k_row(
    float* __restrict__ out, const float* __restrict__ stdp,
    const float* __restrict__ x, const unsigned short* __restrict__ whT,
    const unsigned short* __restrict__ wlT, const float* __restrict__ w2) {
  const int n = blockIdx.x, t = threadIdx.x;
  __shared__ alignas(16) float er[SIDE];
  __shared__ alignas(16) float ec[SIDE];
  __shared__ float rv[4];
  __shared__ float s_red[4];
  __shared__ int cand[128];
  __shared__ int s_ncand;
  __shared__ int s_bmu;
  __shared__ float s_inv;
  float* row = out + (size_t)n * KDIM;

  // pass 1: load row into registers once; block-min
  float4 vals[16];
  float bv = 3.4e38f;
#pragma unroll
  for (int i = 0; i < 16; i++) {
    vals[i] = *(const float4*)(row + (t + i * 256) * 4);
    bv = fminf(fminf(fminf(bv, vals[i].x), fminf(vals[i].y, vals[i].z)), vals[i].w);
  }
#pragma unroll
  for (int off = 32; off > 0; off >>= 1) bv = fminf(bv, __shfl_down(bv, off));
  if ((t & 63) == 0) rv[t >> 6] = bv;
  if (t == 0) s_ncand = 0;
  __syncthreads();
  const float thr = fminf(fminf(rv[0], rv[1]), fminf(rv[2], rv[3])) + 0.05f;

  // pass 2: collect candidates from REGISTERS (no memory re-read)
#pragma unroll
  for (int i = 0; i < 16; i++) {
    int k = (t + i * 256) * 4;
    if (vals[i].x <= thr) { int j = atomicAdd(&s_ncand, 1); if (j < 128) cand[j] = k; }
    if (vals[i].y <= thr) { int j = atomicAdd(&s_ncand, 1); if (j < 128) cand[j] = k + 1; }
    if (vals[i].z <= thr) { int j = atomicAdd(&s_ncand, 1); if (j < 128) cand[j] = k + 2; }
    if (vals[i].w <= thr) { int j = atomicAdd(&s_ncand, 1); if (j < 128) cand[j] = k + 3; }
  }
  __syncthreads();
  int nc = s_ncand < 128 ? s_ncand : 128;

  // refine: exact score = w2[k] - 2 * dot(x_f32, wh+wl) per candidate
  float best = 3.4e38f;
  int bestk = 0x7fffffff;
  const float* xr = x + (size_t)n * CDIM;
  for (int j = 0; j < nc; j++) {
    const int k = cand[j];
    const unsigned short* wh = whT + (size_t)k * CDIM;
    const unsigned short* wl = wlT + (size_t)k * CDIM;
    float s = 0.f;
#pragma unroll
    for (int ii = 0; ii < 2; ii++) {
      int c = (ii * 256 + t) * 8;
      short8 h8 = *(const short8*)(wh + c);
      short8 l8 = *(const short8*)(wl + c);
      float4 xa = *(const float4*)(xr + c);
      float4 xb = *(const float4*)(xr + c + 4);
      s += xa.x * (bf2f((unsigned short)h8[0]) + bf2f((unsigned short)l8[0]));
      s += xa.y * (bf2f((unsigned short)h8[1]) + bf2f((unsigned short)l8[1]));
      s += xa.z * (bf2f((unsigned short)h8[2]) + bf2f((unsigned short)l8[2]));
      s += xa.w * (bf2f((unsigned short)h8[3]) + bf2f((unsigned short)l8[3]));
      s += xb.x * (bf2f((unsigned short)h8[4]) + bf2f((unsigned short)l8[4]));
      s += xb.y * (bf2f((unsigned short)h8[5]) + bf2f((unsigned short)l8[5]));
      s += xb.z * (bf2f((unsigned short)h8[6]) + bf2f((unsigned short)l8[6]));
      s += xb.w * (bf2f((unsigned short)h8[7]) + bf2f((unsigned short)l8[7]));
    }
#pragma unroll
    for (int off = 32; off > 0; off >>= 1) s += __shfl_down(s, off);
    if ((t & 63) == 0) s_red[t >> 6] = s;
    __syncthreads();
    if (t == 0) {
      float dot = s_red[0] + s_red[1] + s_red[2] + s_red[3];
      float sc = w2[k] - 2.0f * dot;
      if (sc < best || (sc == best && k < bestk)) { best = sc; bestk = k; }
    }
    __syncthreads();
  }
  if (t == 0) s_bmu = bestk;
  __syncthreads();

  const int bmu = s_bmu;
  const float sd = stdp[0];
  const float inv2s2 = -0.5f / (sd * sd);
  const float rr = (float)(bmu >> 7), ccol = (float)(bmu & 127);
  if (t < 128) {
    float d = (float)t - rr;
    er[t] = expf(d * d * inv2s2);
  } else {
    int j = t - 128;
    float d = (float)j - ccol;
    ec[j] = expf(d * d * inv2s2);
  }
  __syncthreads();
  if (t == 0) {
    float Sr = 0.f, Sc = 0.f;
    for (int i = 0; i < SIDE; i++) { Sr += er[i]; Sc += ec[i]; }
    s_inv = 1.0f / (Sr * Sc);
  }
  __syncthreads();
  const float inv = s_inv;
#pragma unroll
  for (int i = 0; i < 16; i++) {
    int k = (t + i * 256) * 4;
    float4 v = vals[i];
    float e_r = er[k >> 7] * inv;
    const float4 e4 = *(const float4*)(&ec[k & 127]);
    v.x *= e_r * e4.x;
    v.y *= e_r * e4.y;
    v.z *= e_r * e4.z;
    v.w *= e_r * e4.w;
    *(float4*)(row + k) = v;
  }
}

// ---------- fallback per-row (exact norms2 from k_fb) ----------
__global__ __launch_bounds__(256) void k_row_fb(float* __restrict__ out,
                                                const float* __restrict__ stdp) {
  const int n = blockIdx.x, t = threadIdx.x;
  __shared__ alignas(16) float er[SIDE];
  __shared__ alignas(16) float ec[SIDE];
  __shared__ float rv[4];
  __shared__ int ri[4];
  __shared__ float s_inv;
  __shared__ int s_bmu;
  float* row = out + (size_t)n * KDIM;

  float bv = 3.4e38f;
  int bi = 0;
#pragma unroll 4
  for (int i = 0; i < 16; i++) {
    int k = (t + i * 256) * 4;
    float4 v = *(const float4*)(row + k);
    if (v.x < bv) { bv = v.x; bi = k; }
    if (v.y < bv) { bv = v.y; bi = k + 1; }
    if (v.z < bv) { bv = v.z; bi = k + 2; }
    if (v.w < bv) { bv = v.w; bi = k + 3; }
  }
#pragma unroll
  for (int off = 32; off > 0; off >>= 1) {
    float ov = __shfl_down(bv, off);
    int oi = __shfl_down(bi, off);
    if (ov < bv || (ov == bv && oi < bi)) { bv = ov; bi = oi; }
  }
  if ((t & 63) == 0) { rv[t >> 6] = bv; ri[t >> 6] = bi; }
  __syncthreads();
  if (t == 0) {
    for (int i = 1; i < 4; i++)
      if (rv[i] < bv || (rv[i] == bv && ri[i] < bi)) { bv = rv[i]; bi = ri[i]; }
    s_bmu = bi;
  }
  __syncthreads();
  const int bmu = s_bmu;
  const float sd = stdp[0];
  const float inv2s2 = -0.5f / (sd * sd);
  const float rr = (float)(bmu >> 7), ccol = (float)(bmu & 127);
  if (t < 128) {
    float d = (float)t - rr;
    er[t] = expf(d * d * inv2s2);
  } else {
    int j = t - 128;
    float d = (float)j - ccol;
    ec[j] = expf(d * d * inv2s2);
  }
  __syncthreads();
  if (t == 0) {
    float Sr = 0.f, Sc = 0.f;
    for (int i = 0; i < SIDE; i++) { Sr += er[i]; Sc += ec[i]; }
    s_inv = 1.0f / (Sr * Sc);
  }
  __syncthreads();
  const float inv = s_inv;
#pragma unroll 4
  for (int i = 0; i < 16; i++) {
    int k = (t + i * 256) * 4;
    float4 v = *(const float4*)(row + k);
    float e_r = er[k >> 7] * inv;
    const float4 e4 = *(const float4*)(&ec[k & 127]);
    v.x *= e_r * e4.x;
    v.y *= e_r * e4.y;
    v.z *= e_r * e4.z;
    v.w *= e_r * e4.w;
    *(float4*)(row + k) = v;
  }
}

extern "C" void kernel_launch(void* const* d_in, const int* in_sizes, int n_in,
                              void* d_out, int out_size, void* d_ws, size_t ws_size,
                              hipStream_t stream) {
  (void)in_sizes; (void)n_in; (void)out_size;
  const float* x = (const float*)d_in[0];
  const float* w = (const float*)d_in[1];
  const float* stdp = (const float*)d_in[2];
  float* out = (float*)d_out;

  const size_t sz_wT = (size_t)KDIM * CDIM * sizeof(unsigned short);  // 128 MiB each
  const size_t sz_x  = (size_t)NROWS * CDIM * sizeof(unsigned short); // 8 MiB
  const size_t need = 2 * sz_wT + sz_x + (size_t)NROWS * 4 + (size_t)KDIM * 4;

  if (ws_size >= need) {
    char* p = (char*)d_ws;
    unsigned short* whT = (unsigned short*)p; p += sz_wT;
    unsigned short* wlT = (unsigned short*)p; p += sz_wT;
    unsigned short* xh  = (unsigned short*)p; p += sz_x;
    float* x2 = (float*)p; p += (size_t)NROWS * 4;
    float* w2 = (float*)p;

    // allow 128 KB dynamic LDS for k_gemm (host-side, idempotent, capture-safe)
    static int lds_ok = -1;
    if (lds_ok < 0)
      lds_ok = (int)hipFuncSetAttribute((const void*)k_gemm,
                                        hipFuncAttributeMaxDynamicSharedMemorySize,
                                        131072);

    k_prep<<<NROWS, 256, 0, stream>>>(x, xh, x2, w2);
    k_wconv<<<dim3(KDIM / 64, CDIM / 64), 256, 0, stream>>>(w, whT, wlT, w2);
    k_gemm<<<256, 512, 131072, stream>>>(xh, whT, x2, w2, out);
    k_row<<<NROWS, 256, 0, stream>>>(out, stdp, x, whT, wlT, w2);
  } else {
    k_fb<<<dim3(NROWS / 64, KDIM / 64), 256, 0, stream>>>(x, w, out);
    k_row_fb<<<NROWS, 256, 0, stream>>>(out, stdp);
  }
}